// Round 2
// baseline (9489.529 us; speedup 1.0000x reference)
//
#include <hip/hip_runtime.h>
#include <math.h>

// Problem dims
#define SSRC 50
#define NBATCH 64
#define EDIM 300
#define HDIM 512
#define G4H 2048
#define VTGT 10000
#define TSTEPS 49

// Transposed-interleaved state layout: value (k, n) lives at
//   buf[(k>>2)*256 + n*4 + (k&3)]   i.e. float4 index [k/4][n], lane-coalesced.
#define HS4 8192          // float4 count of one 64x512 state (32768 floats)

// ---------------------------------------------------------------------------
// Device-scope spin barrier (what cg::grid_group::sync lowers to).
// Requires all blocks co-resident: grid=256 blocks on 256 CUs, 16 waves/block,
// LDS <= 66KB, VGPR capped by __launch_bounds__(1024) => >=1 block/CU always.
// Monotone counter, no reset; host memsets counter to 0 before each launch.
// ---------------------------------------------------------------------------
__device__ __forceinline__ void gbar(int* cnt, int nblk, int& gen)
{
    __syncthreads();
    if (threadIdx.x == 0) {
        __threadfence();                                   // release my writes
        __hip_atomic_fetch_add(cnt, 1, __ATOMIC_RELEASE, __HIP_MEMORY_SCOPE_AGENT);
        gen += nblk;
        while (__hip_atomic_load(cnt, __ATOMIC_ACQUIRE, __HIP_MEMORY_SCOPE_AGENT) < gen) {
            __builtin_amdgcn_s_sleep(1);
        }
        __threadfence();                                   // acquire others' writes
    }
    __syncthreads();
}

// ---------------------------------------------------------------------------
// Generic tiled fp32 GEMM: C[m][n] = sum_k A[m][k]*B[n][k] + bias[n]
// A row m optionally gathered (aidx) or transposed (a_trans: A is [K][M], lda=M).
// ---------------------------------------------------------------------------
__global__ __launch_bounds__(256)
void gemm_bias_kernel(const float* __restrict__ A, const int* __restrict__ aidx, int lda,
                      const float* __restrict__ B, int ldb,
                      const float* __restrict__ bias,
                      float* __restrict__ C, int ldc,
                      int M, int N, int K, int a_trans)
{
    __shared__ float As[8][128];
    __shared__ float Bs[8][128];
    const int tid = threadIdx.x;
    const int bm = blockIdx.y * 128;
    const int bn = blockIdx.x * 128;
    const int tx = tid & 15;
    const int ty = tid >> 4;

    float acc[8][8];
#pragma unroll
    for (int i = 0; i < 8; ++i)
#pragma unroll
        for (int j = 0; j < 8; ++j) acc[i][j] = 0.f;

    for (int k0 = 0; k0 < K; k0 += 8) {
#pragma unroll
        for (int i = 0; i < 4; ++i) {
            int idx = tid + i * 256;       // 0..1023
            // A staging
            {
                int r, kk;
                if (a_trans) { r = idx & 127; kk = idx >> 7; }
                else         { r = idx >> 3; kk = idx & 7; }
                int gm = bm + r, gk = k0 + kk;
                float va = 0.f;
                if (gm < M && gk < K) {
                    if (a_trans) va = A[(long)gk * lda + gm];
                    else {
                        long arow = aidx ? (long)aidx[gm] : (long)gm;
                        va = A[arow * (long)lda + gk];
                    }
                }
                As[kk][r] = va;
            }
            // B staging
            {
                int r = idx >> 3, kk = idx & 7;
                int gn = bn + r, gk = k0 + kk;
                float vb = 0.f;
                if (gn < N && gk < K) vb = B[(long)gn * ldb + gk];
                Bs[kk][r] = vb;
            }
        }
        __syncthreads();
#pragma unroll
        for (int kk = 0; kk < 8; ++kk) {
            const float4 a0 = *reinterpret_cast<const float4*>(&As[kk][ty * 8]);
            const float4 a1 = *reinterpret_cast<const float4*>(&As[kk][ty * 8 + 4]);
            const float4 b0 = *reinterpret_cast<const float4*>(&Bs[kk][tx * 8]);
            const float4 b1 = *reinterpret_cast<const float4*>(&Bs[kk][tx * 8 + 4]);
            const float a[8] = {a0.x, a0.y, a0.z, a0.w, a1.x, a1.y, a1.z, a1.w};
            const float b[8] = {b0.x, b0.y, b0.z, b0.w, b1.x, b1.y, b1.z, b1.w};
#pragma unroll
            for (int i = 0; i < 8; ++i)
#pragma unroll
                for (int j = 0; j < 8; ++j)
                    acc[i][j] = fmaf(a[i], b[j], acc[i][j]);
        }
        __syncthreads();
    }

#pragma unroll
    for (int i = 0; i < 8; ++i) {
        int m = bm + ty * 8 + i;
        if (m >= M) continue;
#pragma unroll
        for (int j = 0; j < 8; ++j) {
            int n = bn + tx * 8 + j;
            if (n >= N) continue;
            float v = acc[i][j];
            if (bias) v += bias[n];
            C[(long)m * ldc + n] = v;
        }
    }
}

// ---------------------------------------------------------------------------
// Persistent encoder: 50 bi-LSTM steps + ee + decoder init states.
// 256 blocks x 1024 threads. dir = blk>>7, block owns 4 k-values (kb..kb+3).
// wave w (0..15): k_local = w&3, l-segment = w>>2 (128 l each).
// ---------------------------------------------------------------------------
struct EncArgs {
    const float* Xf; const float* Xb;        // [50][64][2048] (incl. bias)
    const float* Whh_f; const float* Whh_b;  // [2048][512]
    float* hT;    // [2 dir][2 buf][HS4 float4]
    float* cT;    // [2 dir][HS4 float4]
    float* outTf; float* outTb;              // [50][HS4 float4] (outTb pre-reversed)
    const float* energy_W; const float* energy_b;
    float* eeT;   // [50][64]
    const float* fc_hid_W; const float* fc_hid_b;   // [512][1024]
    const float* fc_cell_W; const float* fc_cell_b;
    float* dhT;   // [2 buf][HS4 float4]  (buf0 written here)
    float* dcT;   // [HS4 float4]
    int* bar;
};

__global__ __launch_bounds__(1024)
void enc_persistent(EncArgs a)
{
    __shared__ float W16[512 * 16];          // [l][16]; pos r = kk*4+g holds row j=g*512+kb+kk
    __shared__ float red[4 * 4 * 4 * 64];    // [kl][g][ls][n]
    const int blk = blockIdx.x;
    const int tid = threadIdx.x;
    const int n   = tid & 63;
    const int w   = tid >> 6;
    const int kl  = w & 3;
    const int ls  = w >> 2;
    const int dir = blk >> 7;
    const int kb  = (blk & 127) * 4;
    int gen = 0;

    const float* Whh = dir ? a.Whh_b : a.Whh_f;
    const float* X   = dir ? a.Xb    : a.Xf;
    float* hTd  = a.hT + (size_t)dir * 2 * 4 * HS4;
    float* cTd  = a.cT + (size_t)dir * 4 * HS4;
    float* outT = dir ? a.outTb : a.outTf;

    for (int e = tid; e < 16 * 512; e += 1024) {
        int r = e >> 9, l = e & 511;
        int j = (r & 3) * 512 + kb + (r >> 2);
        W16[l * 16 + r] = Whh[(size_t)j * 512 + l];
    }
    __syncthreads();

    for (int t = 0; t < SSRC; ++t) {
        const int xoff = dir ? (SSRC - 1 - t) : t;
        const float4* h4 = reinterpret_cast<const float4*>(hTd + (size_t)(t & 1) * 4 * HS4);
        float xg0 = 0.f, xg1 = 0.f, xg2 = 0.f, xg3 = 0.f;
        if (w < 4) {    // preload X early (hides scattered-load latency under the GEMM)
            const float* Xr = X + (size_t)xoff * (NBATCH * G4H) + n * G4H + (kb + w);
            xg0 = Xr[0]; xg1 = Xr[512]; xg2 = Xr[1024]; xg3 = Xr[1536];
        }
        float a0 = 0.f, a1 = 0.f, a2 = 0.f, a3 = 0.f;
        const float* wbase = &W16[kl * 4];
        for (int l4 = ls * 32; l4 < ls * 32 + 32; ++l4) {
            const float4 hv = h4[l4 * 64 + n];
            const float* wl = wbase + l4 * 64;
            const float4 w0 = *reinterpret_cast<const float4*>(wl);
            const float4 w1 = *reinterpret_cast<const float4*>(wl + 16);
            const float4 w2 = *reinterpret_cast<const float4*>(wl + 32);
            const float4 w3 = *reinterpret_cast<const float4*>(wl + 48);
            a0 = fmaf(hv.w, w3.x, fmaf(hv.z, w2.x, fmaf(hv.y, w1.x, fmaf(hv.x, w0.x, a0))));
            a1 = fmaf(hv.w, w3.y, fmaf(hv.z, w2.y, fmaf(hv.y, w1.y, fmaf(hv.x, w0.y, a1))));
            a2 = fmaf(hv.w, w3.z, fmaf(hv.z, w2.z, fmaf(hv.y, w1.z, fmaf(hv.x, w0.z, a2))));
            a3 = fmaf(hv.w, w3.w, fmaf(hv.z, w2.w, fmaf(hv.y, w1.w, fmaf(hv.x, w0.w, a3))));
        }
        red[((kl * 4 + 0) * 4 + ls) * 64 + n] = a0;
        red[((kl * 4 + 1) * 4 + ls) * 64 + n] = a1;
        red[((kl * 4 + 2) * 4 + ls) * 64 + n] = a2;
        red[((kl * 4 + 3) * 4 + ls) * 64 + n] = a3;
        __syncthreads();
        if (w < 4) {
            float g0 = xg0, g1 = xg1, g2 = xg2, g3 = xg3;
#pragma unroll
            for (int q = 0; q < 4; ++q) {
                g0 += red[((w * 4 + 0) * 4 + q) * 64 + n];
                g1 += red[((w * 4 + 1) * 4 + q) * 64 + n];
                g2 += red[((w * 4 + 2) * 4 + q) * 64 + n];
                g3 += red[((w * 4 + 3) * 4 + q) * 64 + n];
            }
            const float si = 1.f / (1.f + __expf(-g0));
            const float sf = 1.f / (1.f + __expf(-g1));
            const float so = 1.f / (1.f + __expf(-g3));
            const float tg = tanhf(g2);
            const int k = kb + w;
            const int ci = (k >> 2) * 256 + n * 4 + (k & 3);
            const float cold = cTd[ci];
            const float cn = sf * cold + si * tg;
            const float hn = so * tanhf(cn);
            cTd[ci] = cn;
            (hTd + (size_t)((t + 1) & 1) * 4 * HS4)[ci] = hn;
            outT[(size_t)xoff * 4 * HS4 + ci] = hn;
        }
        gbar(a.bar, 256, gen);
    }

    // ---- phase 2: ee, decoder init states (final h/c are in buffer 0) ----
    if (blk < SSRC) {
        const int s = blk;
        const float4* f4 = reinterpret_cast<const float4*>(a.outTf + (size_t)s * 4 * HS4);
        const float4* b4 = reinterpret_cast<const float4*>(a.outTb + (size_t)s * 4 * HS4);
        float p = 0.f;
        for (int l4 = w * 8; l4 < w * 8 + 8; ++l4) {
            const float4 fv = f4[l4 * 64 + n];
            const float4 bv = b4[l4 * 64 + n];
            const float4 wf = *reinterpret_cast<const float4*>(a.energy_W + 512 + l4 * 4);
            const float4 wb = *reinterpret_cast<const float4*>(a.energy_W + 1024 + l4 * 4);
            p += fv.x * wf.x + fv.y * wf.y + fv.z * wf.z + fv.w * wf.w;
            p += bv.x * wb.x + bv.y * wb.y + bv.z * wb.z + bv.w * wb.w;
        }
        red[w * 64 + n] = p;
        __syncthreads();
        if (w == 0) {
            float sum = a.energy_b[0];
#pragma unroll
            for (int q = 0; q < 16; ++q) sum += red[q * 64 + n];
            a.eeT[s * 64 + n] = sum;
        }
    } else if (blk >= 64 && blk < 192) {
        // dh0 = concat(hf,hb) @ fc_hid_W.T + b ; dc0 = concat(cf,cb) @ fc_cell_W.T + b
        const bool cell = blk >= 128;
        const int kb2 = (blk & 63) * 8;
        const float* W   = cell ? a.fc_cell_W : a.fc_hid_W;
        const float* bs  = cell ? a.fc_cell_b : a.fc_hid_b;
        const float4* Af = reinterpret_cast<const float4*>(cell ? a.cT : a.hT);
        const float4* Ab = reinterpret_cast<const float4*>(cell ? (a.cT + (size_t)4 * HS4)
                                                                : (a.hT + (size_t)8 * HS4));
        const int kl2 = w >> 1, lh = w & 1;
        const int k = kb2 + kl2;
        const float* Wr = W + (size_t)k * 1024;
        float acc = 0.f;
        for (int l4 = lh * 64; l4 < lh * 64 + 64; ++l4) {
            const float4 av  = Af[l4 * 64 + n];
            const float4 wv  = *reinterpret_cast<const float4*>(Wr + l4 * 4);
            acc += av.x * wv.x + av.y * wv.y + av.z * wv.z + av.w * wv.w;
            const float4 av2 = Ab[l4 * 64 + n];
            const float4 wv2 = *reinterpret_cast<const float4*>(Wr + 512 + l4 * 4);
            acc += av2.x * wv2.x + av2.y * wv2.y + av2.z * wv2.z + av2.w * wv2.w;
        }
        red[(kl2 * 2 + lh) * 64 + n] = acc;
        __syncthreads();
        if (w < 8) {
            const float v = bs[kb2 + w] + red[(w * 2) * 64 + n] + red[(w * 2 + 1) * 64 + n];
            const int k2 = kb2 + w;
            const int ci = (k2 >> 2) * 256 + n * 4 + (k2 & 3);
            (cell ? a.dcT : a.dhT)[ci] = v;
        }
    }
}

// ---------------------------------------------------------------------------
// Persistent decoder: 49 steps of (attention -> gates -> pointwise).
// 256 blocks x 1024 threads. Block owns 2 k-values (kB, kB+1).
// wave w: kk = w&1, l-segment = w>>1 (48 float4 of the 384-float4 A-row).
// Blocks 0..63 additionally compute attention + their 4 ctx float4-columns.
// ---------------------------------------------------------------------------
struct DecArgs {
    const float* Xd;            // [49][64][2048] (emb part + bias)
    const float* Wih;           // dec_Wih [2048][1324], use cols 0..1023
    const float* Whh;           // dec_Whh [2048][512]
    const float* energy_W;      // Wh = first 512
    const float* eeT;           // [50][64]
    const float* outTf; const float* outTb;
    float* dhT;                 // [2 buf][HS4 float4]
    float* dcT;
    float* ctxT;                // [256][64] float4
    float* HsT;                 // [512][3136]
    int* bar;
};

__global__ __launch_bounds__(1024)
void dec_persistent(DecArgs a)
{
    __shared__ float Wd[1536 * 8];           // [l][8]; pos r = kk*4+g holds row j=g*512+kB+kk
    __shared__ float red[2 * 4 * 8 * 64];    // [kk][g][ls][n]
    __shared__ float WhL[512];
    __shared__ float hdl[64];
    const int blk = blockIdx.x;
    const int tid = threadIdx.x;
    const int n   = tid & 63;
    const int w   = tid >> 6;
    const int kk  = w & 1;
    const int ls  = w >> 1;
    const int kB  = blk * 2;
    int gen = 0;

    for (int r = 0; r < 8; ++r) {
        const int j = (r & 3) * 512 + kB + (r >> 2);
        Wd[tid * 8 + r] = a.Wih[(size_t)j * 1324 + tid];
        if (tid < 512) Wd[(1024 + tid) * 8 + r] = a.Whh[(size_t)j * 512 + tid];
    }
    if (tid < 512) WhL[tid] = a.energy_W[tid];
    __syncthreads();

    for (int t = 0; t < TSTEPS; ++t) {
        const float* hc = a.dhT + (size_t)(t & 1) * 4 * HS4;
        float xg0 = 0.f, xg1 = 0.f, xg2 = 0.f, xg3 = 0.f;
        if (w < 2) {
            const float* Xr = a.Xd + (size_t)t * (NBATCH * G4H) + n * G4H + (kB + w);
            xg0 = Xr[0]; xg1 = Xr[512]; xg2 = Xr[1024]; xg3 = Xr[1536];
        }
        if (blk < 64) {
            // hdot[n] = h . Wh  (wave-split over l, LDS reduce)
            const float4* h4 = reinterpret_cast<const float4*>(hc);
            float p = 0.f;
            for (int l4 = w * 8; l4 < w * 8 + 8; ++l4) {
                const float4 hv = h4[l4 * 64 + n];
                const float4 wv = *reinterpret_cast<const float4*>(&WhL[l4 * 4]);
                p += hv.x * wv.x + hv.y * wv.y + hv.z * wv.z + hv.w * wv.w;
            }
            red[w * 64 + n] = p;
            __syncthreads();
            if (w == 0) {
                float s2 = 0.f;
#pragma unroll
                for (int q = 0; q < 16; ++q) s2 += red[q * 64 + n];
                hdl[n] = s2;
            }
            __syncthreads();
            const float hd = hdl[n];
            float m = 0.f;                       // relu >= 0 so max starts at 0
            for (int s2 = 0; s2 < SSRC; ++s2)
                m = fmaxf(m, hd + a.eeT[s2 * 64 + n]);
            float ssum = 0.f;
            for (int s2 = 0; s2 < SSRC; ++s2) {
                float e = hd + a.eeT[s2 * 64 + n];
                e = e > 0.f ? e : 0.f;
                ssum += __expf(e - m);
            }
            const float inv = 1.f / ssum;
            if (w < 4) {                          // this block's 4 ctx float4-columns
                const int l4c = blk * 4 + w;      // 0..255
                const float4* base = (l4c < 128)
                    ? reinterpret_cast<const float4*>(a.outTf) + (size_t)l4c * 64
                    : reinterpret_cast<const float4*>(a.outTb) + (size_t)(l4c - 128) * 64;
                float4 acc{0.f, 0.f, 0.f, 0.f};
                for (int s2 = 0; s2 < SSRC; ++s2) {
                    float e = hd + a.eeT[s2 * 64 + n];
                    e = e > 0.f ? e : 0.f;
                    const float wgt = __expf(e - m) * inv;
                    const float4 sv = base[(size_t)s2 * HS4 + n];
                    acc.x = fmaf(wgt, sv.x, acc.x);
                    acc.y = fmaf(wgt, sv.y, acc.y);
                    acc.z = fmaf(wgt, sv.z, acc.z);
                    acc.w = fmaf(wgt, sv.w, acc.w);
                }
                reinterpret_cast<float4*>(a.ctxT)[l4c * 64 + n] = acc;
            }
        }
        gbar(a.bar, 256, gen);   // ctx ready everywhere

        float a0 = 0.f, a1 = 0.f, a2 = 0.f, a3 = 0.f;
        const float4* ctx4 = reinterpret_cast<const float4*>(a.ctxT);
        const float4* h4g  = reinterpret_cast<const float4*>(hc);
        const float* wbase = &Wd[kk * 4];
        for (int l4 = ls * 48; l4 < ls * 48 + 48; ++l4) {
            const float4 av = (l4 < 256) ? ctx4[l4 * 64 + n] : h4g[(l4 - 256) * 64 + n];
            const float* wl = wbase + l4 * 32;
            const float4 w0 = *reinterpret_cast<const float4*>(wl);
            const float4 w1 = *reinterpret_cast<const float4*>(wl + 8);
            const float4 w2 = *reinterpret_cast<const float4*>(wl + 16);
            const float4 w3 = *reinterpret_cast<const float4*>(wl + 24);
            a0 = fmaf(av.w, w3.x, fmaf(av.z, w2.x, fmaf(av.y, w1.x, fmaf(av.x, w0.x, a0))));
            a1 = fmaf(av.w, w3.y, fmaf(av.z, w2.y, fmaf(av.y, w1.y, fmaf(av.x, w0.y, a1))));
            a2 = fmaf(av.w, w3.z, fmaf(av.z, w2.z, fmaf(av.y, w1.z, fmaf(av.x, w0.z, a2))));
            a3 = fmaf(av.w, w3.w, fmaf(av.z, w2.w, fmaf(av.y, w1.w, fmaf(av.x, w0.w, a3))));
        }
        red[((kk * 4 + 0) * 8 + ls) * 64 + n] = a0;
        red[((kk * 4 + 1) * 8 + ls) * 64 + n] = a1;
        red[((kk * 4 + 2) * 8 + ls) * 64 + n] = a2;
        red[((kk * 4 + 3) * 8 + ls) * 64 + n] = a3;
        __syncthreads();
        if (w < 2) {
            float g0 = xg0, g1 = xg1, g2 = xg2, g3 = xg3;
#pragma unroll
            for (int q = 0; q < 8; ++q) {
                g0 += red[((w * 4 + 0) * 8 + q) * 64 + n];
                g1 += red[((w * 4 + 1) * 8 + q) * 64 + n];
                g2 += red[((w * 4 + 2) * 8 + q) * 64 + n];
                g3 += red[((w * 4 + 3) * 8 + q) * 64 + n];
            }
            const float si = 1.f / (1.f + __expf(-g0));
            const float sf = 1.f / (1.f + __expf(-g1));
            const float so = 1.f / (1.f + __expf(-g3));
            const float tg = tanhf(g2);
            const int k = kB + w;
            const int ci = (k >> 2) * 256 + n * 4 + (k & 3);
            const float cold = a.dcT[ci];
            const float cn = sf * cold + si * tg;
            const float hn = so * tanhf(cn);
            a.dcT[ci] = cn;
            (a.dhT + (size_t)((t + 1) & 1) * 4 * HS4)[ci] = hn;
            a.HsT[(size_t)k * (TSTEPS * NBATCH) + t * 64 + n] = hn;
        }
        gbar(a.bar, 256, gen);   // h ready; also protects red/ctxT reuse
    }
}

// ---------------------------------------------------------------------------
extern "C" void kernel_launch(void* const* d_in, const int* in_sizes, int n_in,
                              void* d_out, int out_size, void* d_ws, size_t ws_size,
                              hipStream_t stream)
{
    const int*   source    = (const int*)  d_in[0];
    const int*   target    = (const int*)  d_in[1];
    const float* enc_emb   = (const float*)d_in[2];
    const float* enc_Wih_f = (const float*)d_in[3];
    const float* enc_Whh_f = (const float*)d_in[4];
    const float* enc_b_f   = (const float*)d_in[5];
    const float* enc_Wih_b = (const float*)d_in[6];
    const float* enc_Whh_b = (const float*)d_in[7];
    const float* enc_b_b   = (const float*)d_in[8];
    const float* fc_hid_W  = (const float*)d_in[9];
    const float* fc_hid_b  = (const float*)d_in[10];
    const float* fc_cell_W = (const float*)d_in[11];
    const float* fc_cell_b = (const float*)d_in[12];
    const float* dec_emb   = (const float*)d_in[13];
    const float* dec_Wih   = (const float*)d_in[14];
    const float* dec_Whh   = (const float*)d_in[15];
    const float* dec_b     = (const float*)d_in[16];
    const float* energy_W  = (const float*)d_in[17];
    const float* energy_b  = (const float*)d_in[18];
    const float* fc_W      = (const float*)d_in[19];
    const float* fc_b      = (const float*)d_in[20];
    float* out = (float*)d_out;

    float* w = (float*)d_ws;
    size_t o = 0;
    auto alloc = [&](size_t nf) { float* p = w + o; o += nf; return p; };
    const size_t HS = (size_t)NBATCH * HDIM;            // 32768 floats
    float* Xf    = alloc((size_t)SSRC * NBATCH * G4H);  // 6.55M
    float* Xb    = alloc((size_t)SSRC * NBATCH * G4H);
    float* outTf = alloc((size_t)SSRC * HS);            // transposed-interleaved
    float* outTb = alloc((size_t)SSRC * HS);            // pre-reversed
    float* hT    = alloc(4 * HS);                       // [dir][buf]
    float* cT    = alloc(2 * HS);
    float* dhT   = alloc(2 * HS);
    float* dcT   = alloc(1 * HS);
    float* eeT   = alloc((size_t)SSRC * NBATCH);
    float* HsT   = alloc((size_t)HDIM * TSTEPS * NBATCH);  // [512][3136]
    int*   bars  = (int*)alloc(8);                      // [0]=enc counter, [4]=dec counter
    float* Xd    = Xf;   // alias: encoder X buffer reused by decoder emb GEMM
    float* ctxT  = hT;   // alias: encoder hT dead once decoder starts

    hipMemsetAsync(hT, 0, 4 * HS * sizeof(float), stream);
    hipMemsetAsync(cT, 0, 2 * HS * sizeof(float), stream);
    hipMemsetAsync(bars, 0, 8 * sizeof(int), stream);
    hipMemsetAsync(out, 0, (size_t)NBATCH * VTGT * sizeof(float), stream);

    // encoder input GEMMs (embedding gather fused): X = emb[source] @ Wih.T + b
    {
        dim3 g(G4H / 128, (SSRC * NBATCH + 127) / 128);
        gemm_bias_kernel<<<g, 256, 0, stream>>>(enc_emb, source, EDIM, enc_Wih_f, EDIM,
                                                enc_b_f, Xf, G4H, SSRC * NBATCH, G4H, EDIM, 0);
        gemm_bias_kernel<<<g, 256, 0, stream>>>(enc_emb, source, EDIM, enc_Wih_b, EDIM,
                                                enc_b_b, Xb, G4H, SSRC * NBATCH, G4H, EDIM, 0);
    }

    // persistent encoder (50 steps + ee + init states)
    {
        EncArgs ea{Xf, Xb, enc_Whh_f, enc_Whh_b, hT, cT, outTf, outTb,
                   energy_W, energy_b, eeT, fc_hid_W, fc_hid_b, fc_cell_W, fc_cell_b,
                   dhT, dcT, bars + 0};
        enc_persistent<<<256, 1024, 0, stream>>>(ea);
    }

    // decoder embedding contribution (reuses Xf buffer; safe: stream-ordered)
    {
        dim3 g(G4H / 128, (TSTEPS * NBATCH + 127) / 128);
        gemm_bias_kernel<<<g, 256, 0, stream>>>(dec_emb, target, EDIM, dec_Wih + 2 * HDIM,
                                                2 * HDIM + EDIM, dec_b, Xd, G4H,
                                                TSTEPS * NBATCH, G4H, EDIM, 0);
    }

    // persistent decoder (49 steps of attention + LSTM)
    {
        DecArgs da{Xd, dec_Wih, dec_Whh, energy_W, eeT, outTf, outTb,
                   dhT, dcT, ctxT, HsT, bars + 1};
        dec_persistent<<<256, 1024, 0, stream>>>(da);
    }

    // deferred output projection: preds = Hs @ fc_W.T + fc_b  -> out[1:]
    // HsT is [K=512][M=3136] (transposed A path).
    {
        dim3 g((VTGT + 127) / 128, (TSTEPS * NBATCH + 127) / 128);
        gemm_bias_kernel<<<g, 256, 0, stream>>>(HsT, nullptr, TSTEPS * NBATCH, fc_W, HDIM,
                                                fc_b, out + (size_t)NBATCH * VTGT, VTGT,
                                                TSTEPS * NBATCH, VTGT, HDIM, 1);
    }
}

// Round 3
// 6285.054 us; speedup vs baseline: 1.5099x; 1.5099x over previous
//
#include <hip/hip_runtime.h>
#include <math.h>

// Problem dims
#define SSRC 50
#define NBATCH 64
#define EDIM 300
#define HDIM 512
#define G4H 2048
#define VTGT 10000
#define TSTEPS 49

// Transposed-interleaved state layout: value (k, n) lives at
//   buf[(k>>2)*256 + n*4 + (k&3)]   i.e. float4 index [k/4][n], lane-coalesced.
#define HS4 8192          // float4 count of one 64x512 state (32768 floats)

// ---------------------------------------------------------------------------
// Device-scope spin barrier, ROCm grid.sync pattern:
//   release fence -> RELAXED add -> RELAXED poll -> single acquire fence.
// (Acquire inside the poll loop = per-iteration L2 invalidate storm; that was
//  the 62 us/barrier bug in the previous round.)
// Timeout insurance: if co-residency is ever violated, bail after ~2 s so the
// bench fails verification instead of hanging the container.
// ---------------------------------------------------------------------------
__device__ __forceinline__ void gbar(int* cnt, int nblk, int& gen)
{
    __syncthreads();
    if (threadIdx.x == 0) {
        __threadfence();                                   // release: drain + L2 writeback
        __hip_atomic_fetch_add(cnt, 1, __ATOMIC_RELAXED, __HIP_MEMORY_SCOPE_AGENT);
        gen += nblk;
        const long t0 = (long)__builtin_amdgcn_s_memrealtime();
        while (__hip_atomic_load(cnt, __ATOMIC_RELAXED, __HIP_MEMORY_SCOPE_AGENT) < gen) {
            __builtin_amdgcn_s_sleep(2);
            if ((long)__builtin_amdgcn_s_memrealtime() - t0 > 200000000L) break;
        }
        __threadfence();                                   // acquire: L1/L2 invalidate (once)
    }
    __syncthreads();
}

// ---------------------------------------------------------------------------
// Generic tiled fp32 GEMM: C[m][n] = sum_k A[m][k]*B[n][k] + bias[n]
// A row m optionally gathered (aidx) or transposed (a_trans: A is [K][M], lda=M).
// ---------------------------------------------------------------------------
__global__ __launch_bounds__(256)
void gemm_bias_kernel(const float* __restrict__ A, const int* __restrict__ aidx, int lda,
                      const float* __restrict__ B, int ldb,
                      const float* __restrict__ bias,
                      float* __restrict__ C, int ldc,
                      int M, int N, int K, int a_trans)
{
    __shared__ float As[8][128];
    __shared__ float Bs[8][128];
    const int tid = threadIdx.x;
    const int bm = blockIdx.y * 128;
    const int bn = blockIdx.x * 128;
    const int tx = tid & 15;
    const int ty = tid >> 4;

    float acc[8][8];
#pragma unroll
    for (int i = 0; i < 8; ++i)
#pragma unroll
        for (int j = 0; j < 8; ++j) acc[i][j] = 0.f;

    for (int k0 = 0; k0 < K; k0 += 8) {
#pragma unroll
        for (int i = 0; i < 4; ++i) {
            int idx = tid + i * 256;       // 0..1023
            // A staging
            {
                int r, kk;
                if (a_trans) { r = idx & 127; kk = idx >> 7; }
                else         { r = idx >> 3; kk = idx & 7; }
                int gm = bm + r, gk = k0 + kk;
                float va = 0.f;
                if (gm < M && gk < K) {
                    if (a_trans) va = A[(long)gk * lda + gm];
                    else {
                        long arow = aidx ? (long)aidx[gm] : (long)gm;
                        va = A[arow * (long)lda + gk];
                    }
                }
                As[kk][r] = va;
            }
            // B staging
            {
                int r = idx >> 3, kk = idx & 7;
                int gn = bn + r, gk = k0 + kk;
                float vb = 0.f;
                if (gn < N && gk < K) vb = B[(long)gn * ldb + gk];
                Bs[kk][r] = vb;
            }
        }
        __syncthreads();
#pragma unroll
        for (int kk = 0; kk < 8; ++kk) {
            const float4 a0 = *reinterpret_cast<const float4*>(&As[kk][ty * 8]);
            const float4 a1 = *reinterpret_cast<const float4*>(&As[kk][ty * 8 + 4]);
            const float4 b0 = *reinterpret_cast<const float4*>(&Bs[kk][tx * 8]);
            const float4 b1 = *reinterpret_cast<const float4*>(&Bs[kk][tx * 8 + 4]);
            const float a[8] = {a0.x, a0.y, a0.z, a0.w, a1.x, a1.y, a1.z, a1.w};
            const float b[8] = {b0.x, b0.y, b0.z, b0.w, b1.x, b1.y, b1.z, b1.w};
#pragma unroll
            for (int i = 0; i < 8; ++i)
#pragma unroll
                for (int j = 0; j < 8; ++j)
                    acc[i][j] = fmaf(a[i], b[j], acc[i][j]);
        }
        __syncthreads();
    }

#pragma unroll
    for (int i = 0; i < 8; ++i) {
        int m = bm + ty * 8 + i;
        if (m >= M) continue;
#pragma unroll
        for (int j = 0; j < 8; ++j) {
            int n = bn + tx * 8 + j;
            if (n >= N) continue;
            float v = acc[i][j];
            if (bias) v += bias[n];
            C[(long)m * ldc + n] = v;
        }
    }
}

// ---------------------------------------------------------------------------
// Persistent encoder: 50 bi-LSTM steps + ee + decoder init states.
// 256 blocks x 1024 threads. dir = blk>>7, block owns 4 k-values (kb..kb+3).
// wave w (0..15): k_local = w&3, l-segment = w>>2 (128 l each).
// Per-direction barriers during the loop (128-block crowd), one full barrier
// before the epilogue that mixes directions.
// ---------------------------------------------------------------------------
struct EncArgs {
    const float* Xf; const float* Xb;        // [50][64][2048] (incl. bias)
    const float* Whh_f; const float* Whh_b;  // [2048][512]
    float* hT;    // [2 dir][2 buf][HS4 float4]
    float* cT;    // [2 dir][HS4 float4]
    float* outTf; float* outTb;              // [50][HS4 float4] (outTb pre-reversed)
    const float* energy_W; const float* energy_b;
    float* eeT;   // [50][64]
    const float* fc_hid_W; const float* fc_hid_b;   // [512][1024]
    const float* fc_cell_W; const float* fc_cell_b;
    float* dhT;   // [2 buf][HS4 float4]  (buf0 written here)
    float* dcT;   // [HS4 float4]
    int* bars;    // [0]=fwd, [1]=bwd, [2]=full
};

__global__ __launch_bounds__(1024)
void enc_persistent(EncArgs a)
{
    __shared__ float W16[512 * 16];          // [l][16]; pos r = kk*4+g holds row j=g*512+kb+kk
    __shared__ float red[4 * 4 * 4 * 64];    // [kl][g][ls][n]
    const int blk = blockIdx.x;
    const int tid = threadIdx.x;
    const int n   = tid & 63;
    const int w   = tid >> 6;
    const int kl  = w & 3;
    const int ls  = w >> 2;
    const int dir = blk >> 7;
    const int kb  = (blk & 127) * 4;
    int genD = 0, genF = 0;

    const float* Whh = dir ? a.Whh_b : a.Whh_f;
    const float* X   = dir ? a.Xb    : a.Xf;
    float* hTd  = a.hT + (size_t)dir * 2 * 4 * HS4;
    float* cTd  = a.cT + (size_t)dir * 4 * HS4;
    float* outT = dir ? a.outTb : a.outTf;

    for (int e = tid; e < 16 * 512; e += 1024) {
        int r = e >> 9, l = e & 511;
        int j = (r & 3) * 512 + kb + (r >> 2);
        W16[l * 16 + r] = Whh[(size_t)j * 512 + l];
    }
    __syncthreads();

    for (int t = 0; t < SSRC; ++t) {
        const int xoff = dir ? (SSRC - 1 - t) : t;
        const float4* h4 = reinterpret_cast<const float4*>(hTd + (size_t)(t & 1) * 4 * HS4);
        float xg0 = 0.f, xg1 = 0.f, xg2 = 0.f, xg3 = 0.f;
        if (w < 4) {    // preload X early (hides scattered-load latency under the GEMM)
            const float* Xr = X + (size_t)xoff * (NBATCH * G4H) + n * G4H + (kb + w);
            xg0 = Xr[0]; xg1 = Xr[512]; xg2 = Xr[1024]; xg3 = Xr[1536];
        }
        float a0 = 0.f, a1 = 0.f, a2 = 0.f, a3 = 0.f;
        const float* wbase = &W16[kl * 4];
        for (int l4 = ls * 32; l4 < ls * 32 + 32; ++l4) {
            const float4 hv = h4[l4 * 64 + n];
            const float* wl = wbase + l4 * 64;
            const float4 w0 = *reinterpret_cast<const float4*>(wl);
            const float4 w1 = *reinterpret_cast<const float4*>(wl + 16);
            const float4 w2 = *reinterpret_cast<const float4*>(wl + 32);
            const float4 w3 = *reinterpret_cast<const float4*>(wl + 48);
            a0 = fmaf(hv.w, w3.x, fmaf(hv.z, w2.x, fmaf(hv.y, w1.x, fmaf(hv.x, w0.x, a0))));
            a1 = fmaf(hv.w, w3.y, fmaf(hv.z, w2.y, fmaf(hv.y, w1.y, fmaf(hv.x, w0.y, a1))));
            a2 = fmaf(hv.w, w3.z, fmaf(hv.z, w2.z, fmaf(hv.y, w1.z, fmaf(hv.x, w0.z, a2))));
            a3 = fmaf(hv.w, w3.w, fmaf(hv.z, w2.w, fmaf(hv.y, w1.w, fmaf(hv.x, w0.w, a3))));
        }
        red[((kl * 4 + 0) * 4 + ls) * 64 + n] = a0;
        red[((kl * 4 + 1) * 4 + ls) * 64 + n] = a1;
        red[((kl * 4 + 2) * 4 + ls) * 64 + n] = a2;
        red[((kl * 4 + 3) * 4 + ls) * 64 + n] = a3;
        __syncthreads();
        if (w < 4) {
            float g0 = xg0, g1 = xg1, g2 = xg2, g3 = xg3;
#pragma unroll
            for (int q = 0; q < 4; ++q) {
                g0 += red[((w * 4 + 0) * 4 + q) * 64 + n];
                g1 += red[((w * 4 + 1) * 4 + q) * 64 + n];
                g2 += red[((w * 4 + 2) * 4 + q) * 64 + n];
                g3 += red[((w * 4 + 3) * 4 + q) * 64 + n];
            }
            const float si = 1.f / (1.f + __expf(-g0));
            const float sf = 1.f / (1.f + __expf(-g1));
            const float so = 1.f / (1.f + __expf(-g3));
            const float tg = tanhf(g2);
            const int k = kb + w;
            const int ci = (k >> 2) * 256 + n * 4 + (k & 3);
            const float cold = cTd[ci];
            const float cn = sf * cold + si * tg;
            const float hn = so * tanhf(cn);
            cTd[ci] = cn;
            (hTd + (size_t)((t + 1) & 1) * 4 * HS4)[ci] = hn;
            outT[(size_t)xoff * 4 * HS4 + ci] = hn;
        }
        gbar(a.bars + dir, 128, genD);     // per-direction barrier
    }
    gbar(a.bars + 2, 256, genF);           // full barrier before mixing directions

    // ---- phase 2: ee, decoder init states (final h/c are in buffer 0) ----
    if (blk < SSRC) {
        const int s = blk;
        const float4* f4 = reinterpret_cast<const float4*>(a.outTf + (size_t)s * 4 * HS4);
        const float4* b4 = reinterpret_cast<const float4*>(a.outTb + (size_t)s * 4 * HS4);
        float p = 0.f;
        for (int l4 = w * 8; l4 < w * 8 + 8; ++l4) {
            const float4 fv = f4[l4 * 64 + n];
            const float4 bv = b4[l4 * 64 + n];
            const float4 wf = *reinterpret_cast<const float4*>(a.energy_W + 512 + l4 * 4);
            const float4 wb = *reinterpret_cast<const float4*>(a.energy_W + 1024 + l4 * 4);
            p += fv.x * wf.x + fv.y * wf.y + fv.z * wf.z + fv.w * wf.w;
            p += bv.x * wb.x + bv.y * wb.y + bv.z * wb.z + bv.w * wb.w;
        }
        red[w * 64 + n] = p;
        __syncthreads();
        if (w == 0) {
            float sum = a.energy_b[0];
#pragma unroll
            for (int q = 0; q < 16; ++q) sum += red[q * 64 + n];
            a.eeT[s * 64 + n] = sum;
        }
    } else if (blk >= 64 && blk < 192) {
        // dh0 = concat(hf,hb) @ fc_hid_W.T + b ; dc0 = concat(cf,cb) @ fc_cell_W.T + b
        const bool cell = blk >= 128;
        const int kb2 = (blk & 63) * 8;
        const float* W   = cell ? a.fc_cell_W : a.fc_hid_W;
        const float* bs  = cell ? a.fc_cell_b : a.fc_hid_b;
        const float4* Af = reinterpret_cast<const float4*>(cell ? a.cT : a.hT);
        const float4* Ab = reinterpret_cast<const float4*>(cell ? (a.cT + (size_t)4 * HS4)
                                                                : (a.hT + (size_t)8 * HS4));
        const int kl2 = w >> 1, lh = w & 1;
        const int k = kb2 + kl2;
        const float* Wr = W + (size_t)k * 1024;
        float acc = 0.f;
        for (int l4 = lh * 64; l4 < lh * 64 + 64; ++l4) {
            const float4 av  = Af[l4 * 64 + n];
            const float4 wv  = *reinterpret_cast<const float4*>(Wr + l4 * 4);
            acc += av.x * wv.x + av.y * wv.y + av.z * wv.z + av.w * wv.w;
            const float4 av2 = Ab[l4 * 64 + n];
            const float4 wv2 = *reinterpret_cast<const float4*>(Wr + 512 + l4 * 4);
            acc += av2.x * wv2.x + av2.y * wv2.y + av2.z * wv2.z + av2.w * wv2.w;
        }
        red[(kl2 * 2 + lh) * 64 + n] = acc;
        __syncthreads();
        if (w < 8) {
            const float v = bs[kb2 + w] + red[(w * 2) * 64 + n] + red[(w * 2 + 1) * 64 + n];
            const int k2 = kb2 + w;
            const int ci = (k2 >> 2) * 256 + n * 4 + (k2 & 3);
            (cell ? a.dcT : a.dhT)[ci] = v;
        }
    }
}

// ---------------------------------------------------------------------------
// Persistent decoder: 49 steps of (attention -> gates -> pointwise).
// 256 blocks x 1024 threads. Block owns 2 k-values (kB, kB+1).
// wave w: kk = w&1, l-segment = w>>1 (48 float4 of the 384-float4 A-row).
// Blocks 0..63 additionally compute attention + their 4 ctx float4-columns.
// eeT (step-invariant) is staged to LDS once.
// ---------------------------------------------------------------------------
struct DecArgs {
    const float* Xd;            // [49][64][2048] (emb part + bias)
    const float* Wih;           // dec_Wih [2048][1324], use cols 0..1023
    const float* Whh;           // dec_Whh [2048][512]
    const float* energy_W;      // Wh = first 512
    const float* eeT;           // [50][64]
    const float* outTf; const float* outTb;
    float* dhT;                 // [2 buf][HS4 float4]
    float* dcT;
    float* ctxT;                // [256][64] float4
    float* HsT;                 // [512][3136]
    int* bar;
};

__global__ __launch_bounds__(1024)
void dec_persistent(DecArgs a)
{
    __shared__ float Wd[1536 * 8];           // [l][8]; pos r = kk*4+g holds row j=g*512+kB+kk
    __shared__ float red[2 * 4 * 8 * 64];    // [kk][g][ls][n]
    __shared__ float WhL[512];
    __shared__ float eeL[SSRC * 64];
    __shared__ float hdl[64];
    const int blk = blockIdx.x;
    const int tid = threadIdx.x;
    const int n   = tid & 63;
    const int w   = tid >> 6;
    const int kk  = w & 1;
    const int ls  = w >> 1;
    const int kB  = blk * 2;
    int gen = 0;

    for (int r = 0; r < 8; ++r) {
        const int j = (r & 3) * 512 + kB + (r >> 2);
        Wd[tid * 8 + r] = a.Wih[(size_t)j * 1324 + tid];
        if (tid < 512) Wd[(1024 + tid) * 8 + r] = a.Whh[(size_t)j * 512 + tid];
    }
    if (tid < 512) WhL[tid] = a.energy_W[tid];
    for (int e = tid; e < SSRC * 64; e += 1024) eeL[e] = a.eeT[e];
    __syncthreads();

    for (int t = 0; t < TSTEPS; ++t) {
        const float* hc = a.dhT + (size_t)(t & 1) * 4 * HS4;
        float xg0 = 0.f, xg1 = 0.f, xg2 = 0.f, xg3 = 0.f;
        if (w < 2) {
            const float* Xr = a.Xd + (size_t)t * (NBATCH * G4H) + n * G4H + (kB + w);
            xg0 = Xr[0]; xg1 = Xr[512]; xg2 = Xr[1024]; xg3 = Xr[1536];
        }
        if (blk < 64) {
            // hdot[n] = h . Wh  (wave-split over l, LDS reduce)
            const float4* h4 = reinterpret_cast<const float4*>(hc);
            float p = 0.f;
            for (int l4 = w * 8; l4 < w * 8 + 8; ++l4) {
                const float4 hv = h4[l4 * 64 + n];
                const float4 wv = *reinterpret_cast<const float4*>(&WhL[l4 * 4]);
                p += hv.x * wv.x + hv.y * wv.y + hv.z * wv.z + hv.w * wv.w;
            }
            red[w * 64 + n] = p;
            __syncthreads();
            if (w == 0) {
                float s2 = 0.f;
#pragma unroll
                for (int q = 0; q < 16; ++q) s2 += red[q * 64 + n];
                hdl[n] = s2;
            }
            __syncthreads();
            const float hd = hdl[n];
            float m = 0.f;                       // relu >= 0 so max starts at 0
            for (int s2 = 0; s2 < SSRC; ++s2)
                m = fmaxf(m, hd + eeL[s2 * 64 + n]);
            float ssum = 0.f;
            for (int s2 = 0; s2 < SSRC; ++s2) {
                float e = hd + eeL[s2 * 64 + n];
                e = e > 0.f ? e : 0.f;
                ssum += __expf(e - m);
            }
            const float inv = 1.f / ssum;
            if (w < 4) {                          // this block's 4 ctx float4-columns
                const int l4c = blk * 4 + w;      // 0..255
                const float4* base = (l4c < 128)
                    ? reinterpret_cast<const float4*>(a.outTf) + (size_t)l4c * 64
                    : reinterpret_cast<const float4*>(a.outTb) + (size_t)(l4c - 128) * 64;
                float4 acc{0.f, 0.f, 0.f, 0.f};
                for (int s2 = 0; s2 < SSRC; ++s2) {
                    float e = hd + eeL[s2 * 64 + n];
                    e = e > 0.f ? e : 0.f;
                    const float wgt = __expf(e - m) * inv;
                    const float4 sv = base[(size_t)s2 * HS4 + n];
                    acc.x = fmaf(wgt, sv.x, acc.x);
                    acc.y = fmaf(wgt, sv.y, acc.y);
                    acc.z = fmaf(wgt, sv.z, acc.z);
                    acc.w = fmaf(wgt, sv.w, acc.w);
                }
                reinterpret_cast<float4*>(a.ctxT)[l4c * 64 + n] = acc;
            }
        }
        gbar(a.bar, 256, gen);   // ctx ready everywhere

        float a0 = 0.f, a1 = 0.f, a2 = 0.f, a3 = 0.f;
        const float4* ctx4 = reinterpret_cast<const float4*>(a.ctxT);
        const float4* h4g  = reinterpret_cast<const float4*>(hc);
        const float* wbase = &Wd[kk * 4];
        for (int l4 = ls * 48; l4 < ls * 48 + 48; ++l4) {
            const float4 av = (l4 < 256) ? ctx4[l4 * 64 + n] : h4g[(l4 - 256) * 64 + n];
            const float* wl = wbase + l4 * 32;
            const float4 w0 = *reinterpret_cast<const float4*>(wl);
            const float4 w1 = *reinterpret_cast<const float4*>(wl + 8);
            const float4 w2 = *reinterpret_cast<const float4*>(wl + 16);
            const float4 w3 = *reinterpret_cast<const float4*>(wl + 24);
            a0 = fmaf(av.w, w3.x, fmaf(av.z, w2.x, fmaf(av.y, w1.x, fmaf(av.x, w0.x, a0))));
            a1 = fmaf(av.w, w3.y, fmaf(av.z, w2.y, fmaf(av.y, w1.y, fmaf(av.x, w0.y, a1))));
            a2 = fmaf(av.w, w3.z, fmaf(av.z, w2.z, fmaf(av.y, w1.z, fmaf(av.x, w0.z, a2))));
            a3 = fmaf(av.w, w3.w, fmaf(av.z, w2.w, fmaf(av.y, w1.w, fmaf(av.x, w0.w, a3))));
        }
        red[((kk * 4 + 0) * 8 + ls) * 64 + n] = a0;
        red[((kk * 4 + 1) * 8 + ls) * 64 + n] = a1;
        red[((kk * 4 + 2) * 8 + ls) * 64 + n] = a2;
        red[((kk * 4 + 3) * 8 + ls) * 64 + n] = a3;
        __syncthreads();
        if (w < 2) {
            float g0 = xg0, g1 = xg1, g2 = xg2, g3 = xg3;
#pragma unroll
            for (int q = 0; q < 8; ++q) {
                g0 += red[((w * 4 + 0) * 8 + q) * 64 + n];
                g1 += red[((w * 4 + 1) * 8 + q) * 64 + n];
                g2 += red[((w * 4 + 2) * 8 + q) * 64 + n];
                g3 += red[((w * 4 + 3) * 8 + q) * 64 + n];
            }
            const float si = 1.f / (1.f + __expf(-g0));
            const float sf = 1.f / (1.f + __expf(-g1));
            const float so = 1.f / (1.f + __expf(-g3));
            const float tg = tanhf(g2);
            const int k = kB + w;
            const int ci = (k >> 2) * 256 + n * 4 + (k & 3);
            const float cold = a.dcT[ci];
            const float cn = sf * cold + si * tg;
            const float hn = so * tanhf(cn);
            a.dcT[ci] = cn;
            (a.dhT + (size_t)((t + 1) & 1) * 4 * HS4)[ci] = hn;
            a.HsT[(size_t)k * (TSTEPS * NBATCH) + t * 64 + n] = hn;
        }
        gbar(a.bar, 256, gen);   // h ready; also protects red/ctxT reuse
    }
}

// ---------------------------------------------------------------------------
extern "C" void kernel_launch(void* const* d_in, const int* in_sizes, int n_in,
                              void* d_out, int out_size, void* d_ws, size_t ws_size,
                              hipStream_t stream)
{
    const int*   source    = (const int*)  d_in[0];
    const int*   target    = (const int*)  d_in[1];
    const float* enc_emb   = (const float*)d_in[2];
    const float* enc_Wih_f = (const float*)d_in[3];
    const float* enc_Whh_f = (const float*)d_in[4];
    const float* enc_b_f   = (const float*)d_in[5];
    const float* enc_Wih_b = (const float*)d_in[6];
    const float* enc_Whh_b = (const float*)d_in[7];
    const float* enc_b_b   = (const float*)d_in[8];
    const float* fc_hid_W  = (const float*)d_in[9];
    const float* fc_hid_b  = (const float*)d_in[10];
    const float* fc_cell_W = (const float*)d_in[11];
    const float* fc_cell_b = (const float*)d_in[12];
    const float* dec_emb   = (const float*)d_in[13];
    const float* dec_Wih   = (const float*)d_in[14];
    const float* dec_Whh   = (const float*)d_in[15];
    const float* dec_b     = (const float*)d_in[16];
    const float* energy_W  = (const float*)d_in[17];
    const float* energy_b  = (const float*)d_in[18];
    const float* fc_W      = (const float*)d_in[19];
    const float* fc_b      = (const float*)d_in[20];
    float* out = (float*)d_out;

    float* w = (float*)d_ws;
    size_t o = 0;
    auto alloc = [&](size_t nf) { float* p = w + o; o += nf; return p; };
    const size_t HS = (size_t)NBATCH * HDIM;            // 32768 floats
    float* Xf    = alloc((size_t)SSRC * NBATCH * G4H);  // 6.55M
    float* Xb    = alloc((size_t)SSRC * NBATCH * G4H);
    float* outTf = alloc((size_t)SSRC * HS);            // transposed-interleaved
    float* outTb = alloc((size_t)SSRC * HS);            // pre-reversed
    float* hT    = alloc(4 * HS);                       // [dir][buf]
    float* cT    = alloc(2 * HS);
    float* dhT   = alloc(2 * HS);
    float* dcT   = alloc(1 * HS);
    float* eeT   = alloc((size_t)SSRC * NBATCH);
    float* HsT   = alloc((size_t)HDIM * TSTEPS * NBATCH);  // [512][3136]
    int*   bars  = (int*)alloc(8);                      // [0]=enc fwd, [1]=enc bwd, [2]=enc full, [3]=dec
    float* Xd    = Xf;   // alias: encoder X buffer reused by decoder emb GEMM
    float* ctxT  = hT;   // alias: encoder hT dead once decoder starts

    hipMemsetAsync(hT, 0, 4 * HS * sizeof(float), stream);
    hipMemsetAsync(cT, 0, 2 * HS * sizeof(float), stream);
    hipMemsetAsync(bars, 0, 8 * sizeof(int), stream);
    hipMemsetAsync(out, 0, (size_t)NBATCH * VTGT * sizeof(float), stream);

    // encoder input GEMMs (embedding gather fused): X = emb[source] @ Wih.T + b
    {
        dim3 g(G4H / 128, (SSRC * NBATCH + 127) / 128);
        gemm_bias_kernel<<<g, 256, 0, stream>>>(enc_emb, source, EDIM, enc_Wih_f, EDIM,
                                                enc_b_f, Xf, G4H, SSRC * NBATCH, G4H, EDIM, 0);
        gemm_bias_kernel<<<g, 256, 0, stream>>>(enc_emb, source, EDIM, enc_Wih_b, EDIM,
                                                enc_b_b, Xb, G4H, SSRC * NBATCH, G4H, EDIM, 0);
    }

    // persistent encoder (50 steps + ee + init states)
    {
        EncArgs ea{Xf, Xb, enc_Whh_f, enc_Whh_b, hT, cT, outTf, outTb,
                   energy_W, energy_b, eeT, fc_hid_W, fc_hid_b, fc_cell_W, fc_cell_b,
                   dhT, dcT, bars};
        enc_persistent<<<256, 1024, 0, stream>>>(ea);
    }

    // decoder embedding contribution (reuses Xf buffer; safe: stream-ordered)
    {
        dim3 g(G4H / 128, (TSTEPS * NBATCH + 127) / 128);
        gemm_bias_kernel<<<g, 256, 0, stream>>>(dec_emb, target, EDIM, dec_Wih + 2 * HDIM,
                                                2 * HDIM + EDIM, dec_b, Xd, G4H,
                                                TSTEPS * NBATCH, G4H, EDIM, 0);
    }

    // persistent decoder (49 steps of attention + LSTM)
    {
        DecArgs da{Xd, dec_Wih, dec_Whh, energy_W, eeT, outTf, outTb,
                   dhT, dcT, ctxT, HsT, bars + 3};
        dec_persistent<<<256, 1024, 0, stream>>>(da);
    }

    // deferred output projection: preds = Hs @ fc_W.T + fc_b  -> out[1:]
    // HsT is [K=512][M=3136] (transposed A path).
    {
        dim3 g((VTGT + 127) / 128, (TSTEPS * NBATCH + 127) / 128);
        gemm_bias_kernel<<<g, 256, 0, stream>>>(HsT, nullptr, TSTEPS * NBATCH, fc_W, HDIM,
                                                fc_b, out + (size_t)NBATCH * VTGT, VTGT,
                                                TSTEPS * NBATCH, VTGT, HDIM, 1);
    }
}

// Round 4
// 4798.571 us; speedup vs baseline: 1.9776x; 1.3098x over previous
//
#include <hip/hip_runtime.h>
#include <math.h>

// Problem dims
#define SSRC 50
#define NBATCH 64
#define EDIM 300
#define HDIM 512
#define G4H 2048
#define VTGT 10000
#define TSTEPS 49

// Transposed-interleaved state layout: value (k, n) lives at
//   buf[(k>>2)*256*4 + (n*4 + (k&3))*...]  i.e. float4 index [k/4][n], lane-coalesced.
#define HS4 8192          // float4 count of one 64x512 state (32768 floats)

// ---------------------------------------------------------------------------
// Agent-coherent (sc1, L2-bypassing, L3-coherent) accessors for MUTABLE shared
// state. Read-only data uses normal cached loads and stays L2-resident because
// the barrier below performs NO cache invalidation.
// ---------------------------------------------------------------------------
__device__ __forceinline__ float ld1_agent(const float* p) {
    return __hip_atomic_load(p, __ATOMIC_RELAXED, __HIP_MEMORY_SCOPE_AGENT);
}
__device__ __forceinline__ void st1_agent(float* p, float v) {
    __hip_atomic_store(p, v, __ATOMIC_RELAXED, __HIP_MEMORY_SCOPE_AGENT);
}
__device__ __forceinline__ float2 ld2_agent(const float* p) {
    unsigned long long u = __hip_atomic_load((const unsigned long long*)p,
                                             __ATOMIC_RELAXED, __HIP_MEMORY_SCOPE_AGENT);
    union { unsigned long long u; float2 f; } c; c.u = u; return c.f;
}
__device__ __forceinline__ void st2_agent(float* p, float x, float y) {
    union { float2 f; unsigned long long u; } c; c.f.x = x; c.f.y = y;
    __hip_atomic_store((unsigned long long*)p, c.u, __ATOMIC_RELAXED, __HIP_MEMORY_SCOPE_AGENT);
}

// ---------------------------------------------------------------------------
// Fence-free device barrier. All cross-block data moves via sc1 accessors, so
// no wbl2/inv is needed: per-wave vmcnt(0) drains write-through stores to the
// coherence point (L3); the relaxed atomic counter provides arrival ordering.
// Timeout: if co-residency is ever violated, bail (~2 s) so the bench fails
// verification instead of hanging.
// ---------------------------------------------------------------------------
__device__ __forceinline__ void gbar(int* cnt, int nblk, int& gen)
{
    asm volatile("s_waitcnt vmcnt(0)" ::: "memory");   // every wave drains its stores
    __syncthreads();
    if (threadIdx.x == 0) {
        __hip_atomic_fetch_add(cnt, 1, __ATOMIC_RELAXED, __HIP_MEMORY_SCOPE_AGENT);
        gen += nblk;
        const long long t0 = (long long)__builtin_amdgcn_s_memrealtime();
        while (__hip_atomic_load(cnt, __ATOMIC_RELAXED, __HIP_MEMORY_SCOPE_AGENT) < gen) {
            __builtin_amdgcn_s_sleep(2);
            if ((long long)__builtin_amdgcn_s_memrealtime() - t0 > 200000000LL) break;
        }
    }
    __syncthreads();
}

// ---------------------------------------------------------------------------
// Generic tiled fp32 GEMM: C[m][n] = sum_k A[m][k]*B[n][k] + bias[n]
// A row m optionally gathered (aidx) or transposed (a_trans: A is [K][M], lda=M).
// LDS XOR-swizzle: read pattern (c = tx*8, kk uniform) was 4-way conflicted and
// stores (kk*128 stride) 8-way; swz gives uniform 2-way (free on CDNA4).
// ---------------------------------------------------------------------------
__device__ __forceinline__ int gswz(int kk, int c) {
    return kk * 128 + ((c ^ (((c >> 6) & 1) << 2)) ^ (kk << 2));
}

__global__ __launch_bounds__(256)
void gemm_bias_kernel(const float* __restrict__ A, const int* __restrict__ aidx, int lda,
                      const float* __restrict__ B, int ldb,
                      const float* __restrict__ bias,
                      float* __restrict__ C, int ldc,
                      int M, int N, int K, int a_trans)
{
    __shared__ float As[8 * 128];
    __shared__ float Bs[8 * 128];
    const int tid = threadIdx.x;
    const int bm = blockIdx.y * 128;
    const int bn = blockIdx.x * 128;
    const int tx = tid & 15;
    const int ty = tid >> 4;

    float acc[8][8];
#pragma unroll
    for (int i = 0; i < 8; ++i)
#pragma unroll
        for (int j = 0; j < 8; ++j) acc[i][j] = 0.f;

    for (int k0 = 0; k0 < K; k0 += 8) {
#pragma unroll
        for (int i = 0; i < 4; ++i) {
            int idx = tid + i * 256;       // 0..1023
            // A staging
            {
                int r, kk;
                if (a_trans) { r = idx & 127; kk = idx >> 7; }
                else         { r = idx >> 3; kk = idx & 7; }
                int gm = bm + r, gk = k0 + kk;
                float va = 0.f;
                if (gm < M && gk < K) {
                    if (a_trans) va = A[(long)gk * lda + gm];
                    else {
                        long arow = aidx ? (long)aidx[gm] : (long)gm;
                        va = A[arow * (long)lda + gk];
                    }
                }
                As[gswz(kk, r)] = va;
            }
            // B staging
            {
                int r = idx >> 3, kk = idx & 7;
                int gn = bn + r, gk = k0 + kk;
                float vb = 0.f;
                if (gn < N && gk < K) vb = B[(long)gn * ldb + gk];
                Bs[gswz(kk, r)] = vb;
            }
        }
        __syncthreads();
#pragma unroll
        for (int kk = 0; kk < 8; ++kk) {
            const float4 a0 = *reinterpret_cast<const float4*>(&As[gswz(kk, ty * 8)]);
            const float4 a1 = *reinterpret_cast<const float4*>(&As[gswz(kk, ty * 8 + 4)]);
            const float4 b0 = *reinterpret_cast<const float4*>(&Bs[gswz(kk, tx * 8)]);
            const float4 b1 = *reinterpret_cast<const float4*>(&Bs[gswz(kk, tx * 8 + 4)]);
            const float a[8] = {a0.x, a0.y, a0.z, a0.w, a1.x, a1.y, a1.z, a1.w};
            const float b[8] = {b0.x, b0.y, b0.z, b0.w, b1.x, b1.y, b1.z, b1.w};
#pragma unroll
            for (int i = 0; i < 8; ++i)
#pragma unroll
                for (int j = 0; j < 8; ++j)
                    acc[i][j] = fmaf(a[i], b[j], acc[i][j]);
        }
        __syncthreads();
    }

#pragma unroll
    for (int i = 0; i < 8; ++i) {
        int m = bm + ty * 8 + i;
        if (m >= M) continue;
#pragma unroll
        for (int j = 0; j < 8; ++j) {
            int n = bn + tx * 8 + j;
            if (n >= N) continue;
            float v = acc[i][j];
            if (bias) v += bias[n];
            C[(long)m * ldc + n] = v;
        }
    }
}

// ---------------------------------------------------------------------------
// Persistent encoder: 50 bi-LSTM steps + ee + decoder init states.
// 256 blocks x 1024 threads. dir = blk>>7, block owns 4 k-values (kb..kb+3).
// wave w (0..15): k_local = w&3, l-segment = w>>2 (128 l each).
// Mutable shared state (hT, cT, outT) via sc1 accessors; weights/X cached.
// ---------------------------------------------------------------------------
struct EncArgs {
    const float* Xf; const float* Xb;        // [50][64][2048] (incl. bias)
    const float* Whh_f; const float* Whh_b;  // [2048][512]
    float* hT;    // [2 dir][2 buf][32768 floats]
    float* cT;    // [2 dir][32768]
    float* outTf; float* outTb;              // [50][32768] (outTb pre-reversed)
    const float* energy_W; const float* energy_b;
    float* eeT;   // [50][64]
    const float* fc_hid_W; const float* fc_hid_b;   // [512][1024]
    const float* fc_cell_W; const float* fc_cell_b;
    float* dhT;   // [2 buf][32768]  (buf0 written here)
    float* dcT;   // [32768]
    int* bars;    // [0]=fwd, [1]=bwd, [2]=full
};

__global__ __launch_bounds__(1024)
void enc_persistent(EncArgs a)
{
    __shared__ float W16[512 * 16];          // [l][16]; pos r = kk*4+g holds row j=g*512+kb+kk
    __shared__ float red[4 * 4 * 4 * 64];    // [kl][g][ls][n]
    const int blk = blockIdx.x;
    const int tid = threadIdx.x;
    const int n   = tid & 63;
    const int w   = tid >> 6;
    const int kl  = w & 3;
    const int ls  = w >> 2;
    const int dir = blk >> 7;
    const int kb  = (blk & 127) * 4;
    int genD = 0, genF = 0;

    const float* Whh = dir ? a.Whh_b : a.Whh_f;
    const float* X   = dir ? a.Xb    : a.Xf;
    float* hTd  = a.hT + (size_t)dir * 2 * 4 * HS4;
    float* cTd  = a.cT + (size_t)dir * 4 * HS4;
    float* outT = dir ? a.outTb : a.outTf;

    for (int e = tid; e < 16 * 512; e += 1024) {
        int r = e >> 9, l = e & 511;
        int j = (r & 3) * 512 + kb + (r >> 2);
        W16[l * 16 + r] = Whh[(size_t)j * 512 + l];
    }
    __syncthreads();

    for (int t = 0; t < SSRC; ++t) {
        const int xoff = dir ? (SSRC - 1 - t) : t;
        const float* hbase = hTd + (size_t)(t & 1) * 4 * HS4;
        float xg0 = 0.f, xg1 = 0.f, xg2 = 0.f, xg3 = 0.f;
        if (w < 4) {    // preload X early (cached, read-only)
            const float* Xr = X + (size_t)xoff * (NBATCH * G4H) + n * G4H + (kb + w);
            xg0 = Xr[0]; xg1 = Xr[512]; xg2 = Xr[1024]; xg3 = Xr[1536];
        }
        float a0 = 0.f, a1 = 0.f, a2 = 0.f, a3 = 0.f;
        const float* wbase = &W16[kl * 4];
        for (int l4 = ls * 32; l4 < ls * 32 + 32; ++l4) {
            const float* hp = hbase + ((size_t)l4 * 64 + n) * 4;
            const float2 hlo = ld2_agent(hp);
            const float2 hhi = ld2_agent(hp + 2);
            const float* wl = wbase + l4 * 64;
            const float4 w0 = *reinterpret_cast<const float4*>(wl);
            const float4 w1 = *reinterpret_cast<const float4*>(wl + 16);
            const float4 w2 = *reinterpret_cast<const float4*>(wl + 32);
            const float4 w3 = *reinterpret_cast<const float4*>(wl + 48);
            a0 = fmaf(hhi.y, w3.x, fmaf(hhi.x, w2.x, fmaf(hlo.y, w1.x, fmaf(hlo.x, w0.x, a0))));
            a1 = fmaf(hhi.y, w3.y, fmaf(hhi.x, w2.y, fmaf(hlo.y, w1.y, fmaf(hlo.x, w0.y, a1))));
            a2 = fmaf(hhi.y, w3.z, fmaf(hhi.x, w2.z, fmaf(hlo.y, w1.z, fmaf(hlo.x, w0.z, a2))));
            a3 = fmaf(hhi.y, w3.w, fmaf(hhi.x, w2.w, fmaf(hlo.y, w1.w, fmaf(hlo.x, w0.w, a3))));
        }
        red[((kl * 4 + 0) * 4 + ls) * 64 + n] = a0;
        red[((kl * 4 + 1) * 4 + ls) * 64 + n] = a1;
        red[((kl * 4 + 2) * 4 + ls) * 64 + n] = a2;
        red[((kl * 4 + 3) * 4 + ls) * 64 + n] = a3;
        __syncthreads();
        if (w < 4) {
            float g0 = xg0, g1 = xg1, g2 = xg2, g3 = xg3;
#pragma unroll
            for (int q = 0; q < 4; ++q) {
                g0 += red[((w * 4 + 0) * 4 + q) * 64 + n];
                g1 += red[((w * 4 + 1) * 4 + q) * 64 + n];
                g2 += red[((w * 4 + 2) * 4 + q) * 64 + n];
                g3 += red[((w * 4 + 3) * 4 + q) * 64 + n];
            }
            const float si = 1.f / (1.f + __expf(-g0));
            const float sf = 1.f / (1.f + __expf(-g1));
            const float so = 1.f / (1.f + __expf(-g3));
            const float tg = tanhf(g2);
            const int k = kb + w;
            const int ci = (k >> 2) * 256 + n * 4 + (k & 3);
            const float cold = ld1_agent(&cTd[ci]);
            const float cn = sf * cold + si * tg;
            const float hn = so * tanhf(cn);
            st1_agent(&cTd[ci], cn);
            st1_agent(&(hTd + (size_t)((t + 1) & 1) * 4 * HS4)[ci], hn);
            st1_agent(&outT[(size_t)xoff * 4 * HS4 + ci], hn);
        }
        gbar(a.bars + dir, 128, genD);     // per-direction barrier
    }
    gbar(a.bars + 2, 256, genF);           // full barrier before mixing directions

    // ---- phase 2: ee, decoder init states (final h/c are in buffer 0) ----
    if (blk < SSRC) {
        const int s = blk;
        const float* f4 = a.outTf + (size_t)s * 4 * HS4;
        const float* b4 = a.outTb + (size_t)s * 4 * HS4;
        float p = 0.f;
        for (int l4 = w * 8; l4 < w * 8 + 8; ++l4) {
            const float* fp = f4 + ((size_t)l4 * 64 + n) * 4;
            const float* bp = b4 + ((size_t)l4 * 64 + n) * 4;
            const float2 f01 = ld2_agent(fp), f23 = ld2_agent(fp + 2);
            const float2 b01 = ld2_agent(bp), b23 = ld2_agent(bp + 2);
            const float4 wf = *reinterpret_cast<const float4*>(a.energy_W + 512 + l4 * 4);
            const float4 wb = *reinterpret_cast<const float4*>(a.energy_W + 1024 + l4 * 4);
            p += f01.x * wf.x + f01.y * wf.y + f23.x * wf.z + f23.y * wf.w;
            p += b01.x * wb.x + b01.y * wb.y + b23.x * wb.z + b23.y * wb.w;
        }
        red[w * 64 + n] = p;
        __syncthreads();
        if (w == 0) {
            float sum = a.energy_b[0];
#pragma unroll
            for (int q = 0; q < 16; ++q) sum += red[q * 64 + n];
            a.eeT[s * 64 + n] = sum;
        }
    } else if (blk >= 64 && blk < 192) {
        // dh0 = concat(hf,hb) @ fc_hid_W.T + b ; dc0 = concat(cf,cb) @ fc_cell_W.T + b
        const bool cell = blk >= 128;
        const int kb2 = (blk & 63) * 8;
        const float* W   = cell ? a.fc_cell_W : a.fc_hid_W;
        const float* bs  = cell ? a.fc_cell_b : a.fc_hid_b;
        const float* Afl = cell ? a.cT : a.hT;                       // dir0 (buf0)
        const float* Abl = cell ? (a.cT + (size_t)4 * HS4) : (a.hT + (size_t)8 * HS4);
        const int kl2 = w >> 1, lh = w & 1;
        const int k = kb2 + kl2;
        const float* Wr = W + (size_t)k * 1024;
        float acc = 0.f;
        for (int l4 = lh * 64; l4 < lh * 64 + 64; ++l4) {
            const float* pA = Afl + ((size_t)l4 * 64 + n) * 4;
            const float2 u01 = ld2_agent(pA), u23 = ld2_agent(pA + 2);
            const float4 wv = *reinterpret_cast<const float4*>(Wr + l4 * 4);
            acc += u01.x * wv.x + u01.y * wv.y + u23.x * wv.z + u23.y * wv.w;
            const float* pB = Abl + ((size_t)l4 * 64 + n) * 4;
            const float2 v01 = ld2_agent(pB), v23 = ld2_agent(pB + 2);
            const float4 wv2 = *reinterpret_cast<const float4*>(Wr + 512 + l4 * 4);
            acc += v01.x * wv2.x + v01.y * wv2.y + v23.x * wv2.z + v23.y * wv2.w;
        }
        red[(kl2 * 2 + lh) * 64 + n] = acc;
        __syncthreads();
        if (w < 8) {
            const float v = bs[kb2 + w] + red[(w * 2) * 64 + n] + red[(w * 2 + 1) * 64 + n];
            const int k2 = kb2 + w;
            const int ci = (k2 >> 2) * 256 + n * 4 + (k2 & 3);
            (cell ? a.dcT : a.dhT)[ci] = v;      // normal store; kernel-end flush
        }
    }
}

// ---------------------------------------------------------------------------
// Persistent decoder: 49 steps of (attention -> gates -> pointwise).
// 256 blocks x 1024 threads. Block owns 2 k-values (kB, kB+1).
// wave w: kk = w&1, l-segment = w>>1 (48 float4 of the 384-float4 A-row).
// Blocks 0..63 additionally compute attention + their 4 ctx float4-columns.
// Mutable shared state (dhT, ctxT) via sc1; dcT/HsT block-private/late.
// Read-only (Wd, WhL, eeL in LDS; Xd, outT in L2) stays cached across steps.
// ---------------------------------------------------------------------------
struct DecArgs {
    const float* Xd;            // [49][64][2048] (emb part + bias)
    const float* Wih;           // dec_Wih [2048][1324], use cols 0..1023
    const float* Whh;           // dec_Whh [2048][512]
    const float* energy_W;      // Wh = first 512
    const float* eeT;           // [50][64]
    const float* outTf; const float* outTb;
    float* dhT;                 // [2 buf][32768]
    float* dcT;
    float* ctxT;                // [256][64] float4 = 65536 floats
    float* HsT;                 // [512][3136]
    int* bar;
};

__global__ __launch_bounds__(1024)
void dec_persistent(DecArgs a)
{
    __shared__ float Wd[1536 * 8];           // [l][8]; pos r = kk*4+g holds row j=g*512+kB+kk
    __shared__ float red[2 * 4 * 8 * 64];    // [kk][g][ls][n]
    __shared__ float WhL[512];
    __shared__ float eeL[SSRC * 64];
    __shared__ float hdl[64];
    const int blk = blockIdx.x;
    const int tid = threadIdx.x;
    const int n   = tid & 63;
    const int w   = tid >> 6;
    const int kk  = w & 1;
    const int ls  = w >> 1;
    const int kB  = blk * 2;
    int gen = 0;

    for (int r = 0; r < 8; ++r) {
        const int j = (r & 3) * 512 + kB + (r >> 2);
        Wd[tid * 8 + r] = a.Wih[(size_t)j * 1324 + tid];
        if (tid < 512) Wd[(1024 + tid) * 8 + r] = a.Whh[(size_t)j * 512 + tid];
    }
    if (tid < 512) WhL[tid] = a.energy_W[tid];
    for (int e = tid; e < SSRC * 64; e += 1024) eeL[e] = a.eeT[e];
    __syncthreads();

    for (int t = 0; t < TSTEPS; ++t) {
        const float* hc = a.dhT + (size_t)(t & 1) * 4 * HS4;
        float xg0 = 0.f, xg1 = 0.f, xg2 = 0.f, xg3 = 0.f;
        if (w < 2) {
            const float* Xr = a.Xd + (size_t)t * (NBATCH * G4H) + n * G4H + (kB + w);
            xg0 = Xr[0]; xg1 = Xr[512]; xg2 = Xr[1024]; xg3 = Xr[1536];
        }
        if (blk < 64) {
            // hdot[n] = h . Wh  (wave-split over l, LDS reduce)
            float p = 0.f;
            for (int l4 = w * 8; l4 < w * 8 + 8; ++l4) {
                const float* hp = hc + ((size_t)l4 * 64 + n) * 4;
                const float2 hlo = ld2_agent(hp), hhi = ld2_agent(hp + 2);
                const float4 wv = *reinterpret_cast<const float4*>(&WhL[l4 * 4]);
                p += hlo.x * wv.x + hlo.y * wv.y + hhi.x * wv.z + hhi.y * wv.w;
            }
            red[w * 64 + n] = p;
            __syncthreads();
            if (w == 0) {
                float s2 = 0.f;
#pragma unroll
                for (int q = 0; q < 16; ++q) s2 += red[q * 64 + n];
                hdl[n] = s2;
            }
            __syncthreads();
            const float hd = hdl[n];
            float m = 0.f;                       // relu >= 0 so max starts at 0
            for (int s2 = 0; s2 < SSRC; ++s2)
                m = fmaxf(m, hd + eeL[s2 * 64 + n]);
            float ssum = 0.f;
            for (int s2 = 0; s2 < SSRC; ++s2) {
                float e = hd + eeL[s2 * 64 + n];
                e = e > 0.f ? e : 0.f;
                ssum += __expf(e - m);
            }
            const float inv = 1.f / ssum;
            if (w < 4) {                          // this block's 4 ctx float4-columns
                const int l4c = blk * 4 + w;      // 0..255
                const float4* base = (l4c < 128)
                    ? reinterpret_cast<const float4*>(a.outTf) + (size_t)l4c * 64
                    : reinterpret_cast<const float4*>(a.outTb) + (size_t)(l4c - 128) * 64;
                float4 acc{0.f, 0.f, 0.f, 0.f};
                for (int s2 = 0; s2 < SSRC; ++s2) {
                    float e = hd + eeL[s2 * 64 + n];
                    e = e > 0.f ? e : 0.f;
                    const float wgt = __expf(e - m) * inv;
                    const float4 sv = base[(size_t)s2 * HS4 + n];   // read-only, L2-cached
                    acc.x = fmaf(wgt, sv.x, acc.x);
                    acc.y = fmaf(wgt, sv.y, acc.y);
                    acc.z = fmaf(wgt, sv.z, acc.z);
                    acc.w = fmaf(wgt, sv.w, acc.w);
                }
                float* cp = a.ctxT + ((size_t)l4c * 64 + n) * 4;
                st2_agent(cp, acc.x, acc.y);
                st2_agent(cp + 2, acc.z, acc.w);
            }
        }
        gbar(a.bar, 256, gen);   // ctx ready everywhere

        float a0 = 0.f, a1 = 0.f, a2 = 0.f, a3 = 0.f;
        const float* wbase = &Wd[kk * 4];
        for (int l4 = ls * 48; l4 < ls * 48 + 48; ++l4) {
            const float* ap = (l4 < 256) ? (a.ctxT + ((size_t)l4 * 64 + n) * 4)
                                         : (hc + ((size_t)(l4 - 256) * 64 + n) * 4);
            const float2 xlo = ld2_agent(ap);
            const float2 xhi = ld2_agent(ap + 2);
            const float* wl = wbase + l4 * 32;
            const float4 w0 = *reinterpret_cast<const float4*>(wl);
            const float4 w1 = *reinterpret_cast<const float4*>(wl + 8);
            const float4 w2 = *reinterpret_cast<const float4*>(wl + 16);
            const float4 w3 = *reinterpret_cast<const float4*>(wl + 24);
            a0 = fmaf(xhi.y, w3.x, fmaf(xhi.x, w2.x, fmaf(xlo.y, w1.x, fmaf(xlo.x, w0.x, a0))));
            a1 = fmaf(xhi.y, w3.y, fmaf(xhi.x, w2.y, fmaf(xlo.y, w1.y, fmaf(xlo.x, w0.y, a1))));
            a2 = fmaf(xhi.y, w3.z, fmaf(xhi.x, w2.z, fmaf(xlo.y, w1.z, fmaf(xlo.x, w0.z, a2))));
            a3 = fmaf(xhi.y, w3.w, fmaf(xhi.x, w2.w, fmaf(xlo.y, w1.w, fmaf(xlo.x, w0.w, a3))));
        }
        red[((kk * 4 + 0) * 8 + ls) * 64 + n] = a0;
        red[((kk * 4 + 1) * 8 + ls) * 64 + n] = a1;
        red[((kk * 4 + 2) * 8 + ls) * 64 + n] = a2;
        red[((kk * 4 + 3) * 8 + ls) * 64 + n] = a3;
        __syncthreads();
        if (w < 2) {
            float g0 = xg0, g1 = xg1, g2 = xg2, g3 = xg3;
#pragma unroll
            for (int q = 0; q < 8; ++q) {
                g0 += red[((w * 4 + 0) * 8 + q) * 64 + n];
                g1 += red[((w * 4 + 1) * 8 + q) * 64 + n];
                g2 += red[((w * 4 + 2) * 8 + q) * 64 + n];
                g3 += red[((w * 4 + 3) * 8 + q) * 64 + n];
            }
            const float si = 1.f / (1.f + __expf(-g0));
            const float sf = 1.f / (1.f + __expf(-g1));
            const float so = 1.f / (1.f + __expf(-g3));
            const float tg = tanhf(g2);
            const int k = kB + w;
            const int ci = (k >> 2) * 256 + n * 4 + (k & 3);
            const float cold = a.dcT[ci];        // block-private: normal cached
            const float cn = sf * cold + si * tg;
            const float hn = so * tanhf(cn);
            a.dcT[ci] = cn;
            st1_agent(&(a.dhT + (size_t)((t + 1) & 1) * 4 * HS4)[ci], hn);
            a.HsT[(size_t)k * (TSTEPS * NBATCH) + t * 64 + n] = hn;  // read post-kernel
        }
        gbar(a.bar, 256, gen);   // h ready; also protects red/ctxT reuse
    }
}

// ---------------------------------------------------------------------------
extern "C" void kernel_launch(void* const* d_in, const int* in_sizes, int n_in,
                              void* d_out, int out_size, void* d_ws, size_t ws_size,
                              hipStream_t stream)
{
    const int*   source    = (const int*)  d_in[0];
    const int*   target    = (const int*)  d_in[1];
    const float* enc_emb   = (const float*)d_in[2];
    const float* enc_Wih_f = (const float*)d_in[3];
    const float* enc_Whh_f = (const float*)d_in[4];
    const float* enc_b_f   = (const float*)d_in[5];
    const float* enc_Wih_b = (const float*)d_in[6];
    const float* enc_Whh_b = (const float*)d_in[7];
    const float* enc_b_b   = (const float*)d_in[8];
    const float* fc_hid_W  = (const float*)d_in[9];
    const float* fc_hid_b  = (const float*)d_in[10];
    const float* fc_cell_W = (const float*)d_in[11];
    const float* fc_cell_b = (const float*)d_in[12];
    const float* dec_emb   = (const float*)d_in[13];
    const float* dec_Wih   = (const float*)d_in[14];
    const float* dec_Whh   = (const float*)d_in[15];
    const float* dec_b     = (const float*)d_in[16];
    const float* energy_W  = (const float*)d_in[17];
    const float* energy_b  = (const float*)d_in[18];
    const float* fc_W      = (const float*)d_in[19];
    const float* fc_b      = (const float*)d_in[20];
    float* out = (float*)d_out;

    float* w = (float*)d_ws;
    size_t o = 0;
    auto alloc = [&](size_t nf) { float* p = w + o; o += nf; return p; };
    const size_t HS = (size_t)NBATCH * HDIM;            // 32768 floats
    float* Xf    = alloc((size_t)SSRC * NBATCH * G4H);  // 6.55M
    float* Xb    = alloc((size_t)SSRC * NBATCH * G4H);
    float* outTf = alloc((size_t)SSRC * HS);            // transposed-interleaved
    float* outTb = alloc((size_t)SSRC * HS);            // pre-reversed
    float* hT    = alloc(4 * HS);                       // [dir][buf]
    float* cT    = alloc(2 * HS);
    float* dhT   = alloc(2 * HS);
    float* dcT   = alloc(1 * HS);
    float* eeT   = alloc((size_t)SSRC * NBATCH);
    float* HsT   = alloc((size_t)HDIM * TSTEPS * NBATCH);  // [512][3136]
    int*   bars  = (int*)alloc(8);                      // [0]=enc fwd, [1]=enc bwd, [2]=enc full, [3]=dec
    float* Xd    = Xf;   // alias: encoder X buffer reused by decoder emb GEMM
    float* ctxT  = hT;   // alias: encoder hT dead once decoder starts

    hipMemsetAsync(hT, 0, 4 * HS * sizeof(float), stream);
    hipMemsetAsync(cT, 0, 2 * HS * sizeof(float), stream);
    hipMemsetAsync(bars, 0, 8 * sizeof(int), stream);
    hipMemsetAsync(out, 0, (size_t)NBATCH * VTGT * sizeof(float), stream);

    // encoder input GEMMs (embedding gather fused): X = emb[source] @ Wih.T + b
    {
        dim3 g(G4H / 128, (SSRC * NBATCH + 127) / 128);
        gemm_bias_kernel<<<g, 256, 0, stream>>>(enc_emb, source, EDIM, enc_Wih_f, EDIM,
                                                enc_b_f, Xf, G4H, SSRC * NBATCH, G4H, EDIM, 0);
        gemm_bias_kernel<<<g, 256, 0, stream>>>(enc_emb, source, EDIM, enc_Wih_b, EDIM,
                                                enc_b_b, Xb, G4H, SSRC * NBATCH, G4H, EDIM, 0);
    }

    // persistent encoder (50 steps + ee + init states)
    {
        EncArgs ea{Xf, Xb, enc_Whh_f, enc_Whh_b, hT, cT, outTf, outTb,
                   energy_W, energy_b, eeT, fc_hid_W, fc_hid_b, fc_cell_W, fc_cell_b,
                   dhT, dcT, bars};
        enc_persistent<<<256, 1024, 0, stream>>>(ea);
    }

    // decoder embedding contribution (reuses Xf buffer; safe: stream-ordered)
    {
        dim3 g(G4H / 128, (TSTEPS * NBATCH + 127) / 128);
        gemm_bias_kernel<<<g, 256, 0, stream>>>(dec_emb, target, EDIM, dec_Wih + 2 * HDIM,
                                                2 * HDIM + EDIM, dec_b, Xd, G4H,
                                                TSTEPS * NBATCH, G4H, EDIM, 0);
    }

    // persistent decoder (49 steps of attention + LSTM)
    {
        DecArgs da{Xd, dec_Wih, dec_Whh, energy_W, eeT, outTf, outTb,
                   dhT, dcT, ctxT, HsT, bars + 3};
        dec_persistent<<<256, 1024, 0, stream>>>(da);
    }

    // deferred output projection: preds = Hs @ fc_W.T + fc_b  -> out[1:]
    // HsT is [K=512][M=3136] (transposed A path).
    {
        dim3 g((VTGT + 127) / 128, (TSTEPS * NBATCH + 127) / 128);
        gemm_bias_kernel<<<g, 256, 0, stream>>>(HsT, nullptr, TSTEPS * NBATCH, fc_W, HDIM,
                                                fc_b, out + (size_t)NBATCH * VTGT, VTGT,
                                                TSTEPS * NBATCH, VTGT, HDIM, 1);
    }
}

// Round 5
// 4653.855 us; speedup vs baseline: 2.0391x; 1.0311x over previous
//
#include <hip/hip_runtime.h>
#include <math.h>

// Problem dims
#define SSRC 50
#define NBATCH 64
#define EDIM 300
#define HDIM 512
#define G4H 2048
#define VTGT 10000
#define TSTEPS 49

// Transposed-interleaved state layout: value (k, n) lives at float index
//   (k>>2)*256 + n*4 + (k&3)   i.e. float4 index [k/4][n], lane-coalesced.
#define HS4 8192          // float4 count of one 64x512 state (32768 floats)

// ---------------------------------------------------------------------------
// Agent-coherent (sc1, L2-bypassing, L3-coherent) accessors for MUTABLE shared
// state. Read-only data uses normal cached loads and stays L2-resident because
// the barrier below performs NO cache invalidation.
// ---------------------------------------------------------------------------
__device__ __forceinline__ float ld1_agent(const float* p) {
    return __hip_atomic_load(p, __ATOMIC_RELAXED, __HIP_MEMORY_SCOPE_AGENT);
}
__device__ __forceinline__ void st1_agent(float* p, float v) {
    __hip_atomic_store(p, v, __ATOMIC_RELAXED, __HIP_MEMORY_SCOPE_AGENT);
}
__device__ __forceinline__ float2 ld2_agent(const float* p) {
    unsigned long long u = __hip_atomic_load((const unsigned long long*)p,
                                             __ATOMIC_RELAXED, __HIP_MEMORY_SCOPE_AGENT);
    union { unsigned long long u; float2 f; } c; c.u = u; return c.f;
}
__device__ __forceinline__ void st2_agent(float* p, float x, float y) {
    union { float2 f; unsigned long long u; } c; c.f.x = x; c.f.y = y;
    __hip_atomic_store((unsigned long long*)p, c.u, __ATOMIC_RELAXED, __HIP_MEMORY_SCOPE_AGENT);
}

// ---------------------------------------------------------------------------
// Fence-free device barrier (R4-verified). sc1 traffic drains via vmcnt(0);
// relaxed counter, relaxed poll, no cache maintenance. Timeout so a residency
// violation fails verification instead of hanging.
// ---------------------------------------------------------------------------
__device__ __forceinline__ void gbar(int* cnt, int nblk, int& gen)
{
    asm volatile("s_waitcnt vmcnt(0)" ::: "memory");
    __syncthreads();
    if (threadIdx.x == 0) {
        __hip_atomic_fetch_add(cnt, 1, __ATOMIC_RELAXED, __HIP_MEMORY_SCOPE_AGENT);
        gen += nblk;
        const long long t0 = (long long)__builtin_amdgcn_s_memrealtime();
        while (__hip_atomic_load(cnt, __ATOMIC_RELAXED, __HIP_MEMORY_SCOPE_AGENT) < gen) {
            __builtin_amdgcn_s_sleep(2);
            if ((long long)__builtin_amdgcn_s_memrealtime() - t0 > 200000000LL) break;
        }
    }
    __syncthreads();
}

// ---------------------------------------------------------------------------
// Generic tiled fp32 GEMM (unchanged from R4, incl. LDS XOR-swizzle).
// ---------------------------------------------------------------------------
__device__ __forceinline__ int gswz(int kk, int c) {
    return kk * 128 + ((c ^ (((c >> 6) & 1) << 2)) ^ (kk << 2));
}

__global__ __launch_bounds__(256)
void gemm_bias_kernel(const float* __restrict__ A, const int* __restrict__ aidx, int lda,
                      const float* __restrict__ B, int ldb,
                      const float* __restrict__ bias,
                      float* __restrict__ C, int ldc,
                      int M, int N, int K, int a_trans)
{
    __shared__ float As[8 * 128];
    __shared__ float Bs[8 * 128];
    const int tid = threadIdx.x;
    const int bm = blockIdx.y * 128;
    const int bn = blockIdx.x * 128;
    const int tx = tid & 15;
    const int ty = tid >> 4;

    float acc[8][8];
#pragma unroll
    for (int i = 0; i < 8; ++i)
#pragma unroll
        for (int j = 0; j < 8; ++j) acc[i][j] = 0.f;

    for (int k0 = 0; k0 < K; k0 += 8) {
#pragma unroll
        for (int i = 0; i < 4; ++i) {
            int idx = tid + i * 256;
            {
                int r, kk;
                if (a_trans) { r = idx & 127; kk = idx >> 7; }
                else         { r = idx >> 3; kk = idx & 7; }
                int gm = bm + r, gk = k0 + kk;
                float va = 0.f;
                if (gm < M && gk < K) {
                    if (a_trans) va = A[(long)gk * lda + gm];
                    else {
                        long arow = aidx ? (long)aidx[gm] : (long)gm;
                        va = A[arow * (long)lda + gk];
                    }
                }
                As[gswz(kk, r)] = va;
            }
            {
                int r = idx >> 3, kk = idx & 7;
                int gn = bn + r, gk = k0 + kk;
                float vb = 0.f;
                if (gn < N && gk < K) vb = B[(long)gn * ldb + gk];
                Bs[gswz(kk, r)] = vb;
            }
        }
        __syncthreads();
#pragma unroll
        for (int kk = 0; kk < 8; ++kk) {
            const float4 a0 = *reinterpret_cast<const float4*>(&As[gswz(kk, ty * 8)]);
            const float4 a1 = *reinterpret_cast<const float4*>(&As[gswz(kk, ty * 8 + 4)]);
            const float4 b0 = *reinterpret_cast<const float4*>(&Bs[gswz(kk, tx * 8)]);
            const float4 b1 = *reinterpret_cast<const float4*>(&Bs[gswz(kk, tx * 8 + 4)]);
            const float a[8] = {a0.x, a0.y, a0.z, a0.w, a1.x, a1.y, a1.z, a1.w};
            const float b[8] = {b0.x, b0.y, b0.z, b0.w, b1.x, b1.y, b1.z, b1.w};
#pragma unroll
            for (int i = 0; i < 8; ++i)
#pragma unroll
                for (int j = 0; j < 8; ++j)
                    acc[i][j] = fmaf(a[i], b[j], acc[i][j]);
        }
        __syncthreads();
    }

#pragma unroll
    for (int i = 0; i < 8; ++i) {
        int m = bm + ty * 8 + i;
        if (m >= M) continue;
#pragma unroll
        for (int j = 0; j < 8; ++j) {
            int n = bn + tx * 8 + j;
            if (n >= N) continue;
            float v = acc[i][j];
            if (bias) v += bias[n];
            C[(long)m * ldc + n] = v;
        }
    }
}

// ---------------------------------------------------------------------------
// Weight pre-transpose kernels. Per-block tile layout, float4 = 4 l-values:
//  enc: WtE f4 idx ((dir*16+jg)*128 + l4)*128 + jj,  jj: gate=jj&3, kl=jj>>2,
//       j_global = gate*512 + jg*32 + kl, value = Whh[j_global][l4*4..+3]
//  dec: WtD f4 idx (jg*384 + l4)*64 + j,  j: gate=j&3, kl=j>>2,
//       j_global = gate*512 + jg*16 + kl; l<1024 from Wih, else Whh.
// ---------------------------------------------------------------------------
__global__ __launch_bounds__(256)
void enc_wt_kernel(const float* __restrict__ Wf, const float* __restrict__ Wb,
                   float4* __restrict__ Wt)
{
    const int F = blockIdx.x * 256 + threadIdx.x;
    if (F >= 2 * 16 * 128 * 128) return;
    const int jj = F & 127;
    const int l4 = (F >> 7) & 127;
    const int r  = F >> 14;                 // dir*16 + jg
    const int dir = r >> 4, jg = r & 15;
    const int jglob = (jj & 3) * 512 + jg * 32 + (jj >> 2);
    const float* src = dir ? Wb : Wf;
    Wt[F] = *reinterpret_cast<const float4*>(src + (size_t)jglob * 512 + l4 * 4);
}

__global__ __launch_bounds__(256)
void dec_wt_kernel(const float* __restrict__ Wih, const float* __restrict__ Whh,
                   float4* __restrict__ Wt)
{
    const int F = blockIdx.x * 256 + threadIdx.x;
    if (F >= 32 * 384 * 64) return;
    const int j = F & 63;
    const int t = F >> 6;                   // jg*384 + l4
    const int l4 = t % 384, jg = t / 384;
    const int jglob = (j & 3) * 512 + jg * 16 + (j >> 2);
    const int l = l4 * 4;
    float4 v;
    if (l < 1024) v = *reinterpret_cast<const float4*>(Wih + (size_t)jglob * 1324 + l);
    else          v = *reinterpret_cast<const float4*>(Whh + (size_t)jglob * 512 + (l - 1024));
    Wt[F] = v;
}

// ---------------------------------------------------------------------------
// Persistent encoder: 256 blocks = 2 dir x (16 jg x 8 ng). Block computes
// gates[8n][128 rows = 32k x 4g] over K=512. Activation slice (16 KB) via sc1;
// weight tile (256 KB) streamed from L2 (cached, step-invariant, XCD-local).
// ---------------------------------------------------------------------------
struct EncArgs {
    const float* Xf; const float* Xb;        // [50][64][2048] (incl. bias)
    const float4* WtE;                       // transposed enc weights
    float* hT;    // [2 dir][2 buf][32768]
    float* cT;    // [2 dir][32768]
    float* outTf; float* outTb;              // [50][32768] (outTb pre-reversed)
    const float* energy_W; const float* energy_b;
    float* eeT;   // [50][64]
    const float* fc_hid_W; const float* fc_hid_b;
    const float* fc_cell_W; const float* fc_cell_b;
    float* dhT;   // [2 buf][32768]
    float* dcT;   // [32768]
    int* bars;    // [0]=fwd, [1]=bwd, [2]=full
};

__global__ __launch_bounds__(1024)
void enc_persistent(EncArgs a)
{
    __shared__ float actL[8 * 516];          // [n^][512 l] padded
    __shared__ float red[8 * 8 * 128];       // [lc][n^][jj]  32 KB
    const int blk = blockIdx.x;
    const int tid = threadIdx.x;
    const int lane = tid & 63;
    const int w    = tid >> 6;
    const int lc   = w >> 1;
    const int jh   = w & 1;
    const int dir  = blk >> 7;
    const int db   = blk & 127;
    const int jg   = (db & 7) * 2 + (db >> 6);   // XCD-local weight tiles
    const int ng   = (db >> 3) & 7;
    int genD = 0, genF = 0;

    const float* X   = dir ? a.Xb : a.Xf;
    float* hTd  = a.hT + (size_t)dir * 2 * 4 * HS4;
    float* cTd  = a.cT + (size_t)dir * 4 * HS4;
    float* outT = dir ? a.outTb : a.outTf;
    const float4* Wt = a.WtE + (size_t)(dir * 16 + jg) * 128 * 128;

    // pointwise role (tid < 256): n^ = tid>>5, kl = tid&31
    const int pw_n  = ng * 8 + (tid >> 5);
    const int pw_kl = tid & 31;
    const int pw_k  = jg * 32 + pw_kl;
    const int pw_ci = (pw_k >> 2) * 256 + pw_n * 4 + (pw_k & 3);

    for (int t = 0; t < SSRC; ++t) {
        const int xoff = dir ? (SSRC - 1 - t) : t;
        const float* hbase = hTd + (size_t)(t & 1) * 4 * HS4;
        float xg0 = 0.f, xg1 = 0.f, xg2 = 0.f, xg3 = 0.f;
        if (tid < 256) {                     // X preload (cached, read-only)
            const float* Xr = X + (size_t)xoff * (NBATCH * G4H) + pw_n * G4H + pw_k;
            xg0 = Xr[0]; xg1 = Xr[512]; xg2 = Xr[1024]; xg3 = Xr[1536];
        }
        // stage h slice [8n][512] -> LDS (sc1, coalesced 128B chunks)
        {
            const int nh = tid & 7, l4g = tid >> 3;     // l4g 0..127
            const float* hp = hbase + ((size_t)l4g * 64 + ng * 8 + nh) * 4;
            const float2 lo = ld2_agent(hp), hi = ld2_agent(hp + 2);
            float4 v; v.x = lo.x; v.y = lo.y; v.z = hi.x; v.w = hi.y;
            *reinterpret_cast<float4*>(&actL[nh * 516 + l4g * 4]) = v;
        }
        __syncthreads();
        // GEMM: wave (lc, jh): l4 in [lc*16, lc*16+16), rows jj = jh*64+lane
        float acc[8];
#pragma unroll
        for (int q = 0; q < 8; ++q) acc[q] = 0.f;
        {
            const float4* wp = Wt + (size_t)(lc * 16) * 128 + jh * 64 + lane;
            for (int i = 0; i < 16; ++i) {
                const float4 wv = wp[(size_t)i * 128];
                const int l4 = lc * 16 + i;
#pragma unroll
                for (int q = 0; q < 8; ++q) {
                    const float4 av = *reinterpret_cast<const float4*>(&actL[q * 516 + l4 * 4]);
                    acc[q] = fmaf(av.w, wv.w, fmaf(av.z, wv.z,
                              fmaf(av.y, wv.y, fmaf(av.x, wv.x, acc[q]))));
                }
            }
        }
#pragma unroll
        for (int q = 0; q < 8; ++q) red[lc * 1024 + q * 128 + jh * 64 + lane] = acc[q];
        __syncthreads();
        if (tid < 256) {
            const int nh = tid >> 5;
            float g0 = xg0, g1 = xg1, g2 = xg2, g3 = xg3;
#pragma unroll
            for (int l2 = 0; l2 < 8; ++l2) {
                const float* rp = &red[l2 * 1024 + nh * 128 + pw_kl * 4];
                g0 += rp[0]; g1 += rp[1]; g2 += rp[2]; g3 += rp[3];
            }
            const float si = 1.f / (1.f + __expf(-g0));
            const float sf = 1.f / (1.f + __expf(-g1));
            const float so = 1.f / (1.f + __expf(-g3));
            const float tg = tanhf(g2);
            const float cold = ld1_agent(&cTd[pw_ci]);
            const float cn = sf * cold + si * tg;
            const float hn = so * tanhf(cn);
            st1_agent(&cTd[pw_ci], cn);
            st1_agent(&(hTd + (size_t)((t + 1) & 1) * 4 * HS4)[pw_ci], hn);
            st1_agent(&outT[(size_t)xoff * 4 * HS4 + pw_ci], hn);
        }
        gbar(a.bars + dir, 128, genD);
    }
    gbar(a.bars + 2, 256, genF);

    // ---- phase 2: ee + decoder init states (final h/c in buffer 0) ----
    const int n = lane;
    if (blk < SSRC) {
        const int s = blk;
        const float* f4 = a.outTf + (size_t)s * 4 * HS4;
        const float* b4 = a.outTb + (size_t)s * 4 * HS4;
        float p = 0.f;
        for (int l4 = w * 8; l4 < w * 8 + 8; ++l4) {
            const float* fp = f4 + ((size_t)l4 * 64 + n) * 4;
            const float* bp = b4 + ((size_t)l4 * 64 + n) * 4;
            const float2 f01 = ld2_agent(fp), f23 = ld2_agent(fp + 2);
            const float2 b01 = ld2_agent(bp), b23 = ld2_agent(bp + 2);
            const float4 wf = *reinterpret_cast<const float4*>(a.energy_W + 512 + l4 * 4);
            const float4 wb = *reinterpret_cast<const float4*>(a.energy_W + 1024 + l4 * 4);
            p += f01.x * wf.x + f01.y * wf.y + f23.x * wf.z + f23.y * wf.w;
            p += b01.x * wb.x + b01.y * wb.y + b23.x * wb.z + b23.y * wb.w;
        }
        red[w * 64 + n] = p;
        __syncthreads();
        if (w == 0) {
            float sum = a.energy_b[0];
#pragma unroll
            for (int q = 0; q < 16; ++q) sum += red[q * 64 + n];
            a.eeT[s * 64 + n] = sum;
        }
    } else if (blk >= 64 && blk < 192) {
        const bool cell = blk >= 128;
        const int kb2 = (blk & 63) * 8;
        const float* W   = cell ? a.fc_cell_W : a.fc_hid_W;
        const float* bs  = cell ? a.fc_cell_b : a.fc_hid_b;
        const float* Afl = cell ? a.cT : a.hT;                       // dir0 buf0
        const float* Abl = cell ? (a.cT + (size_t)4 * HS4) : (a.hT + (size_t)8 * HS4);
        const int kl2 = w >> 1, lh = w & 1;
        const int k = kb2 + kl2;
        const float* Wr = W + (size_t)k * 1024;
        float acc = 0.f;
        for (int l4 = lh * 64; l4 < lh * 64 + 64; ++l4) {
            const float* pA = Afl + ((size_t)l4 * 64 + n) * 4;
            const float2 u01 = ld2_agent(pA), u23 = ld2_agent(pA + 2);
            const float4 wv = *reinterpret_cast<const float4*>(Wr + l4 * 4);
            acc += u01.x * wv.x + u01.y * wv.y + u23.x * wv.z + u23.y * wv.w;
            const float* pB = Abl + ((size_t)l4 * 64 + n) * 4;
            const float2 v01 = ld2_agent(pB), v23 = ld2_agent(pB + 2);
            const float4 wv2 = *reinterpret_cast<const float4*>(Wr + 512 + l4 * 4);
            acc += v01.x * wv2.x + v01.y * wv2.y + v23.x * wv2.z + v23.y * wv2.w;
        }
        red[(kl2 * 2 + lh) * 64 + n] = acc;
        __syncthreads();
        if (w < 8) {
            const float v = bs[kb2 + w] + red[(w * 2) * 64 + n] + red[(w * 2 + 1) * 64 + n];
            const int k2 = kb2 + w;
            const int ci = (k2 >> 2) * 256 + n * 4 + (k2 & 3);
            (cell ? a.dcT : a.dhT)[ci] = v;      // normal store; kernel-end flush
        }
    }
}

// ---------------------------------------------------------------------------
// Persistent decoder: 256 blocks = 32 jg x 8 ng. Per step:
//   blk<64: attention (hdot, softmax, 4 ctx cols) | all: stage h slice
//   bar -> stage ctx slice -> gate GEMM (weights from L2, acts from LDS)
//   -> combine + LSTM pointwise -> bar.
// ---------------------------------------------------------------------------
struct DecArgs {
    const float* Xd;            // [49][64][2048] (emb part + bias)
    const float4* WtD;          // transposed dec weights [32][384][64] f4
    const float* energy_W;      // Wh = first 512
    const float* eeT;           // [50][64]
    const float* outTf; const float* outTb;
    float* dhT;                 // [2 buf][32768]
    float* dcT;
    float* ctxT;                // f4 [256][64]
    float* HsT;                 // [512][3136]
    int* bar;
};

__global__ __launch_bounds__(1024)
void dec_persistent(DecArgs a)
{
    __shared__ float actL[8 * 1540];         // [n^][1536 l] padded, 49.3 KB
    __shared__ float red[16 * 8 * 64];       // [w][n^][j]  32 KB
    __shared__ float WhL[512];
    __shared__ float eeL[SSRC * 64];
    __shared__ float hdl[64];
    const int blk = blockIdx.x;
    const int tid = threadIdx.x;
    const int lane = tid & 63;
    const int w    = tid >> 6;
    const int jg   = (blk & 7) * 4 + (blk >> 6);    // XCD-local weight tiles
    const int ng   = (blk >> 3) & 7;
    int gen = 0;
    const float4* Wt = a.WtD + (size_t)jg * 384 * 64;

    if (tid < 512) WhL[tid] = a.energy_W[tid];
    for (int e = tid; e < SSRC * 64; e += 1024) eeL[e] = a.eeT[e];
    __syncthreads();

    // pointwise role (tid < 128): n^ = tid>>4, kl = tid&15
    const int pw_nh = tid >> 4;
    const int pw_kl = tid & 15;
    const int pw_n  = ng * 8 + pw_nh;
    const int pw_k  = jg * 16 + pw_kl;
    const int pw_ci = (pw_k >> 2) * 256 + pw_n * 4 + (pw_k & 3);

    for (int t = 0; t < TSTEPS; ++t) {
        const float* hc = a.dhT + (size_t)(t & 1) * 4 * HS4;
        float xg0 = 0.f, xg1 = 0.f, xg2 = 0.f, xg3 = 0.f;
        if (tid < 128) {
            const float* Xr = a.Xd + (size_t)t * (NBATCH * G4H) + pw_n * G4H + pw_k;
            xg0 = Xr[0]; xg1 = Xr[512]; xg2 = Xr[1024]; xg3 = Xr[1536];
        }
        if (blk < 64) {
            // hdot[n] = h . Wh (wave-split over l, LDS reduce)
            float p = 0.f;
            for (int l4 = w * 8; l4 < w * 8 + 8; ++l4) {
                const float* hp = hc + ((size_t)l4 * 64 + lane) * 4;
                const float2 lo = ld2_agent(hp), hi = ld2_agent(hp + 2);
                const float4 wv = *reinterpret_cast<const float4*>(&WhL[l4 * 4]);
                p += lo.x * wv.x + lo.y * wv.y + hi.x * wv.z + hi.y * wv.w;
            }
            red[w * 64 + lane] = p;
            __syncthreads();
            if (w == 0) {
                float s2 = 0.f;
#pragma unroll
                for (int q = 0; q < 16; ++q) s2 += red[q * 64 + lane];
                hdl[lane] = s2;
            }
            __syncthreads();
            if (w < 4) {
                const float hd = hdl[lane];
                float m = 0.f;                   // relu >= 0
                for (int s2 = 0; s2 < SSRC; ++s2)
                    m = fmaxf(m, hd + eeL[s2 * 64 + lane]);
                float ssum = 0.f;
                for (int s2 = 0; s2 < SSRC; ++s2) {
                    float e = hd + eeL[s2 * 64 + lane];
                    e = e > 0.f ? e : 0.f;
                    ssum += __expf(e - m);
                }
                const float inv = 1.f / ssum;
                const int l4c = blk * 4 + w;
                const float4* base = (l4c < 128)
                    ? reinterpret_cast<const float4*>(a.outTf) + (size_t)l4c * 64
                    : reinterpret_cast<const float4*>(a.outTb) + (size_t)(l4c - 128) * 64;
                float4 acc4{0.f, 0.f, 0.f, 0.f};
                for (int s2 = 0; s2 < SSRC; ++s2) {
                    float e = hd + eeL[s2 * 64 + lane];
                    e = e > 0.f ? e : 0.f;
                    const float wgt = __expf(e - m) * inv;
                    const float4 sv = base[(size_t)s2 * HS4 + lane];   // cached
                    acc4.x = fmaf(wgt, sv.x, acc4.x);
                    acc4.y = fmaf(wgt, sv.y, acc4.y);
                    acc4.z = fmaf(wgt, sv.z, acc4.z);
                    acc4.w = fmaf(wgt, sv.w, acc4.w);
                }
                float* cp = a.ctxT + ((size_t)l4c * 64 + lane) * 4;
                st2_agent(cp, acc4.x, acc4.y);
                st2_agent(cp + 2, acc4.z, acc4.w);
            }
        }
        // stage h part of activation slice (l4g 256..383) before the barrier
        {
            const int nh = tid & 7, l4g = 256 + (tid >> 3);
            const float* hp = hc + ((size_t)(l4g - 256) * 64 + ng * 8 + nh) * 4;
            const float2 lo = ld2_agent(hp), hi = ld2_agent(hp + 2);
            float4 v; v.x = lo.x; v.y = lo.y; v.z = hi.x; v.w = hi.y;
            *reinterpret_cast<float4*>(&actL[nh * 1540 + l4g * 4]) = v;
        }
        gbar(a.bar, 256, gen);   // ctx ready
        // stage ctx part (l4g 0..255): 2 f4 per thread
#pragma unroll
        for (int i = 0; i < 2; ++i) {
            const int e = tid + i * 1024;
            const int nh = e & 7, l4g = e >> 3;
            const float* cp = a.ctxT + ((size_t)l4g * 64 + ng * 8 + nh) * 4;
            const float2 lo = ld2_agent(cp), hi = ld2_agent(cp + 2);
            float4 v; v.x = lo.x; v.y = lo.y; v.z = hi.x; v.w = hi.y;
            *reinterpret_cast<float4*>(&actL[nh * 1540 + l4g * 4]) = v;
        }
        __syncthreads();
        // gate GEMM: wave w handles l4 in [w*24, w*24+24), lane = row j
        float acc[8];
#pragma unroll
        for (int q = 0; q < 8; ++q) acc[q] = 0.f;
        {
            const float4* wp = Wt + (size_t)(w * 24) * 64 + lane;
            for (int i = 0; i < 24; ++i) {
                const float4 wv = wp[(size_t)i * 64];
                const int l4 = w * 24 + i;
#pragma unroll
                for (int q = 0; q < 8; ++q) {
                    const float4 av = *reinterpret_cast<const float4*>(&actL[q * 1540 + l4 * 4]);
                    acc[q] = fmaf(av.w, wv.w, fmaf(av.z, wv.z,
                              fmaf(av.y, wv.y, fmaf(av.x, wv.x, acc[q]))));
                }
            }
        }
#pragma unroll
        for (int q = 0; q < 8; ++q) red[w * 512 + q * 64 + lane] = acc[q];
        __syncthreads();
        if (tid < 128) {
            float g0 = xg0, g1 = xg1, g2 = xg2, g3 = xg3;
#pragma unroll
            for (int w2 = 0; w2 < 16; ++w2) {
                const float* rp = &red[w2 * 512 + pw_nh * 64 + pw_kl * 4];
                g0 += rp[0]; g1 += rp[1]; g2 += rp[2]; g3 += rp[3];
            }
            const float si = 1.f / (1.f + __expf(-g0));
            const float sf = 1.f / (1.f + __expf(-g1));
            const float so = 1.f / (1.f + __expf(-g3));
            const float tg = tanhf(g2);
            const float cold = a.dcT[pw_ci];     // block-private, cached
            const float cn = sf * cold + si * tg;
            const float hn = so * tanhf(cn);
            a.dcT[pw_ci] = cn;
            st1_agent(&(a.dhT + (size_t)((t + 1) & 1) * 4 * HS4)[pw_ci], hn);
            // sc1: two ng-blocks share 64B lines here -> no cached writeback
            st1_agent(&a.HsT[(size_t)pw_k * (TSTEPS * NBATCH) + t * 64 + pw_n], hn);
        }
        gbar(a.bar, 256, gen);   // h ready; protects red/ctxT/actL reuse
    }
}

// ---------------------------------------------------------------------------
extern "C" void kernel_launch(void* const* d_in, const int* in_sizes, int n_in,
                              void* d_out, int out_size, void* d_ws, size_t ws_size,
                              hipStream_t stream)
{
    const int*   source    = (const int*)  d_in[0];
    const int*   target    = (const int*)  d_in[1];
    const float* enc_emb   = (const float*)d_in[2];
    const float* enc_Wih_f = (const float*)d_in[3];
    const float* enc_Whh_f = (const float*)d_in[4];
    const float* enc_b_f   = (const float*)d_in[5];
    const float* enc_Wih_b = (const float*)d_in[6];
    const float* enc_Whh_b = (const float*)d_in[7];
    const float* enc_b_b   = (const float*)d_in[8];
    const float* fc_hid_W  = (const float*)d_in[9];
    const float* fc_hid_b  = (const float*)d_in[10];
    const float* fc_cell_W = (const float*)d_in[11];
    const float* fc_cell_b = (const float*)d_in[12];
    const float* dec_emb   = (const float*)d_in[13];
    const float* dec_Wih   = (const float*)d_in[14];
    const float* dec_Whh   = (const float*)d_in[15];
    const float* dec_b     = (const float*)d_in[16];
    const float* energy_W  = (const float*)d_in[17];
    const float* energy_b  = (const float*)d_in[18];
    const float* fc_W      = (const float*)d_in[19];
    const float* fc_b      = (const float*)d_in[20];
    float* out = (float*)d_out;

    float* w = (float*)d_ws;
    size_t o = 0;
    auto alloc = [&](size_t nf) { float* p = w + o; o += nf; return p; };
    const size_t HS = (size_t)NBATCH * HDIM;            // 32768 floats
    float* Xf    = alloc((size_t)SSRC * NBATCH * G4H);  // 6.55M
    float* Xb    = alloc((size_t)SSRC * NBATCH * G4H);
    float* outTf = alloc((size_t)SSRC * HS);
    float* outTb = alloc((size_t)SSRC * HS);            // pre-reversed
    float* hT    = alloc(4 * HS);
    float* cT    = alloc(2 * HS);
    float* dhT   = alloc(2 * HS);
    float* dcT   = alloc(1 * HS);
    float* eeT   = alloc((size_t)SSRC * NBATCH);
    float* HsT   = alloc((size_t)HDIM * TSTEPS * NBATCH);   // [512][3136]
    float* WtE   = alloc((size_t)2 * 16 * 128 * 512);       // 2.10M floats
    int*   bars  = (int*)alloc(16);
    float* Xd    = Xf;   // alias: enc X buffer reused for decoder emb GEMM
    float* ctxT  = hT;   // alias: encoder hT dead once decoder starts
    float* WtD   = Xb;   // alias: Xb dead after encoder; 3.15M <= 6.55M

    hipMemsetAsync(hT, 0, 4 * HS * sizeof(float), stream);
    hipMemsetAsync(cT, 0, 2 * HS * sizeof(float), stream);
    hipMemsetAsync(bars, 0, 16 * sizeof(int), stream);
    hipMemsetAsync(out, 0, (size_t)NBATCH * VTGT * sizeof(float), stream);

    // encoder input GEMMs (embedding gather fused): X = emb[source] @ Wih.T + b
    {
        dim3 g(G4H / 128, (SSRC * NBATCH + 127) / 128);
        gemm_bias_kernel<<<g, 256, 0, stream>>>(enc_emb, source, EDIM, enc_Wih_f, EDIM,
                                                enc_b_f, Xf, G4H, SSRC * NBATCH, G4H, EDIM, 0);
        gemm_bias_kernel<<<g, 256, 0, stream>>>(enc_emb, source, EDIM, enc_Wih_b, EDIM,
                                                enc_b_b, Xb, G4H, SSRC * NBATCH, G4H, EDIM, 0);
    }
    // encoder weight transpose
    enc_wt_kernel<<<(2 * 16 * 128 * 128 + 255) / 256, 256, 0, stream>>>(
        enc_Whh_f, enc_Whh_b, (float4*)WtE);

    // persistent encoder (50 steps + ee + init states)
    {
        EncArgs ea{Xf, Xb, (const float4*)WtE, hT, cT, outTf, outTb,
                   energy_W, energy_b, eeT, fc_hid_W, fc_hid_b, fc_cell_W, fc_cell_b,
                   dhT, dcT, bars};
        enc_persistent<<<256, 1024, 0, stream>>>(ea);
    }

    // decoder embedding contribution (reuses Xf buffer)
    {
        dim3 g(G4H / 128, (TSTEPS * NBATCH + 127) / 128);
        gemm_bias_kernel<<<g, 256, 0, stream>>>(dec_emb, target, EDIM, dec_Wih + 2 * HDIM,
                                                2 * HDIM + EDIM, dec_b, Xd, G4H,
                                                TSTEPS * NBATCH, G4H, EDIM, 0);
    }
    // decoder weight transpose (into dead Xb space)
    dec_wt_kernel<<<(32 * 384 * 64 + 255) / 256, 256, 0, stream>>>(
        dec_Wih, dec_Whh, (float4*)WtD);

    // persistent decoder (49 steps of attention + LSTM)
    {
        DecArgs da{Xd, (const float4*)WtD, energy_W, eeT, outTf, outTb,
                   dhT, dcT, ctxT, HsT, bars + 3};
        dec_persistent<<<256, 1024, 0, stream>>>(da);
    }

    // deferred output projection: preds = Hs @ fc_W.T + fc_b -> out[1:]
    // HsT is [K=512][M=3136] (transposed A path).
    {
        dim3 g((VTGT + 127) / 128, (TSTEPS * NBATCH + 127) / 128);
        gemm_bias_kernel<<<g, 256, 0, stream>>>(HsT, nullptr, TSTEPS * NBATCH, fc_W, HDIM,
                                                fc_b, out + (size_t)NBATCH * VTGT, VTGT,
                                                TSTEPS * NBATCH, VTGT, HDIM, 1);
    }
}